// Round 12
// baseline (171.619 us; speedup 1.0000x reference)
//
#include <hip/hip_runtime.h>
#include <hip/hip_bf16.h>

#define S_LEN 2048
#define B_SZ  16
#define F_DIM 256
#define NROWS (S_LEN * B_SZ)   // 32768

typedef unsigned short ushort_t;
typedef unsigned int   uint_t;
typedef __attribute__((ext_vector_type(8))) short bf16x8;
typedef __attribute__((ext_vector_type(4))) float f32x4;

__device__ __forceinline__ ushort_t f2bf(float f) {
    uint_t x = __float_as_uint(f);
    uint_t r = x + 0x7fffu + ((x >> 16) & 1u);
    return (ushort_t)(r >> 16);
}

__device__ __forceinline__ bf16x8 pack8(float4 a, float4 b) {
    union { bf16x8 v; __hip_bfloat162 h[4]; } u;
    u.h[0] = __float22bfloat162_rn(make_float2(a.x, a.y));
    u.h[1] = __float22bfloat162_rn(make_float2(a.z, a.w));
    u.h[2] = __float22bfloat162_rn(make_float2(b.x, b.y));
    u.h[3] = __float22bfloat162_rn(make_float2(b.z, b.w));
    return u.v;
}

// async 16B global -> LDS (HW writes lds_base + lane*16; gaddr is per-lane)
__device__ __forceinline__ void async_copy16(const ushort_t* g, ushort_t* l) {
    __builtin_amdgcn_global_load_lds(
        (const __attribute__((address_space(1))) uint_t*)g,
        (__attribute__((address_space(3))) uint_t*)l,
        16, 0, 0);
}

// ---------------------------------------------------------------------------
// Kernel 0: one-time W -> bf16 (q,k,v).  Scratch = d_out (attn overwrites all
// of out afterwards; same-stream ordering -> deterministic every replay).
// ---------------------------------------------------------------------------
__global__ __launch_bounds__(256) void wconv_kernel(
    const float* __restrict__ Wq, const float* __restrict__ Wk,
    const float* __restrict__ Wv, ushort_t* __restrict__ Wbf)
{
    const int idx = blockIdx.x * 256 + threadIdx.x;
    const int mat = idx >> 13;
    const int off = (idx & 8191) * 8;
    const float* W = (mat == 0) ? Wq : (mat == 1) ? Wk : Wv;
    const float4 f0 = *reinterpret_cast<const float4*>(&W[off + 0]);
    const float4 f1 = *reinterpret_cast<const float4*>(&W[off + 4]);
    *reinterpret_cast<bf16x8*>(&Wbf[mat * 65536 + off]) = pack8(f0, f1);
}

// ---------------------------------------------------------------------------
// Kernel 1: MFMA QKV projection (unchanged, R9-proven).  Q pre-scaled 1/16.
// ---------------------------------------------------------------------------
__global__ __launch_bounds__(256, 2) void qkv_proj_mfma_kernel(
    const float* __restrict__ x,
    const ushort_t* __restrict__ Wbf,
    const float* __restrict__ bq, const float* __restrict__ bk,
    const float* __restrict__ bv,
    ushort_t* __restrict__ Qd, ushort_t* __restrict__ Kd, ushort_t* __restrict__ Vtd)
{
    __shared__ ushort_t Xs[64 * 256];

    const int tid = threadIdx.x;
    const int w   = tid >> 6;
    const int l   = tid & 63;
    const int lo  = l & 15;
    const int hi  = l >> 4;
    const int bid = blockIdx.x;
    const int bm  = (bid & 7) * 64 + (bid >> 3);
    const int r0  = bm * 64;
    const int wcol0 = w * 64;

    {
        const int row0  = tid >> 3;
        const int slot0 = (tid & 7) * 4;
        #pragma unroll
        for (int p = 0; p < 2; ++p) {
            const int row = row0 + p * 32;
            const float* xrow = &x[(size_t)(r0 + row) * F_DIM];
            #pragma unroll
            for (int c = 0; c < 4; ++c) {
                const int slot = slot0 + c;
                const float4 f0 = *reinterpret_cast<const float4*>(&xrow[slot * 8 + 0]);
                const float4 f1 = *reinterpret_cast<const float4*>(&xrow[slot * 8 + 4]);
                *reinterpret_cast<bf16x8*>(&Xs[row * 256 + ((slot ^ (row & 7)) * 8)]) = pack8(f0, f1);
            }
        }
    }
    __syncthreads();

    const float* Bias[3] = {bq, bk, bv};

    for (int mat = 0; mat < 3; ++mat) {
        const ushort_t* Wm  = &Wbf[mat * 65536];
        const float*    bias = Bias[mat];

        f32x4 acc[4][4];
        #pragma unroll
        for (int m = 0; m < 4; ++m)
            #pragma unroll
            for (int ks = 0; ks < 4; ++ks) acc[m][ks] = (f32x4){0.f, 0.f, 0.f, 0.f};

        #pragma unroll
        for (int ks = 0; ks < 4; ++ks) {
            bf16x8 wf[8];
            {
                const ushort_t* wrow = &Wm[(size_t)(wcol0 + ks * 16 + lo) * F_DIM + hi * 8];
                #pragma unroll
                for (int c = 0; c < 8; ++c)
                    wf[c] = *reinterpret_cast<const bf16x8*>(&wrow[c * 32]);
            }
            #pragma unroll
            for (int m = 0; m < 4; ++m) {
                const int arow = m * 16 + lo;
                const ushort_t* abase = &Xs[arow * 256];
                const int rx = arow & 7;
                #pragma unroll
                for (int c = 0; c < 8; ++c) {
                    const bf16x8 af = *reinterpret_cast<const bf16x8*>(
                        &abase[((c * 4 + hi) ^ rx) * 8]);
                    acc[m][ks] = __builtin_amdgcn_mfma_f32_16x16x32_bf16(af, wf[c], acc[m][ks], 0, 0, 0);
                }
            }
        }

        if (mat < 2) {
            ushort_t* Y = (mat == 0) ? Qd : Kd;
            const float osc = (mat == 0) ? 0.0625f : 1.0f;
            #pragma unroll
            for (int ks = 0; ks < 4; ++ks) {
                const int col = wcol0 + ks * 16 + lo;
                const float bv_ = bias[col];
                #pragma unroll
                for (int m = 0; m < 4; ++m) {
                    #pragma unroll
                    for (int r = 0; r < 4; ++r) {
                        const int row = r0 + m * 16 + hi * 4 + r;
                        Y[(size_t)row * F_DIM + col] = f2bf((acc[m][ks][r] + bv_) * osc);
                    }
                }
            }
        } else {
            const int s0 = r0 >> 4;
            #pragma unroll
            for (int ks = 0; ks < 4; ++ks) {
                const int f = wcol0 + ks * 16 + lo;
                const float bv_ = bias[f];
                #pragma unroll
                for (int r = 0; r < 4; ++r) {
                    const int b = hi * 4 + r;
                    ushort4 u;
                    u.x = f2bf(acc[0][ks][r] + bv_);
                    u.y = f2bf(acc[1][ks][r] + bv_);
                    u.z = f2bf(acc[2][ks][r] + bv_);
                    u.w = f2bf(acc[3][ks][r] + bv_);
                    *reinterpret_cast<ushort4*>(&Vtd[((size_t)b * F_DIM + f) * S_LEN + s0]) = u;
                }
            }
        }
    }
}

// ---------------------------------------------------------------------------
// Kernel 2: MFMA flash attention — 4 waves x 32 q-rows (2 m-subtiles).  Each
// kf/vf b128 LDS read now feeds TWO MFMAs (m=0,1): per-tile LDS traffic drops
// 540->278 KB (R11 was LDS-BW-bound at 8x16).  Async zero-register staging
// via global_load_lds (pre-swizzled global source, linear LDS dest), single
// raw s_barrier per tile, counted-free vmcnt(0) (loads had full tile to
// land).  Swapped QK^T + b64 P-write + softmax-lite: proven paths, per-m.
// LDS: 2*(32+32) + 16 = 144 KB; 256 thr, 1 wave/SIMD, ~250 VGPR budget.
// ---------------------------------------------------------------------------
__global__ __launch_bounds__(256, 1) void attn_mfma_kernel(
    const ushort_t* __restrict__ Qd,
    const ushort_t* __restrict__ Kd,
    const ushort_t* __restrict__ Vtd,
    float* __restrict__ out)
{
    __shared__ ushort_t Ks[2][64 * 256];    // 2 x 32 KB
    __shared__ ushort_t Vts[2][256 * 64];   // 2 x 32 KB
    __shared__ short    Ps[4][2][16 * 64];  // 2 KB per wave per m-subtile

    const int tid = threadIdx.x;
    const int w   = tid >> 6;            // 0..3
    const int l   = tid & 63;
    const int lo  = l & 15;
    const int hi  = l >> 4;

    const int fid = blockIdx.x;
    const int xcd = fid & 7;
    const int i   = fid >> 3;
    const int b   = xcd * 2 + (i >> 4);
    const int q0  = (i & 15) * 128;
    const int qw  = q0 + w * 32;         // wave owns 32 q-rows

    const int kslot = tid & 31;
    const int vslot = tid & 7;

    // STAGE: 8 K passes + 8 V passes x 256 threads x 16B.  LDS dest linear
    // (pass*2048 + w*512 elements, HW adds lane*16B); global address carries
    // the inverse swizzle so the swizzled READ layout (slot ^ row&7) holds.
    auto STAGE = [&](int t, int bufi) {
        #pragma unroll
        for (int p = 0; p < 8; ++p) {
            const int row  = p * 8 + (tid >> 5);             // 0..63
            const int col8 = kslot ^ (row & 7);
            async_copy16(&Kd[((size_t)(t + row) * B_SZ + b) * F_DIM + col8 * 8],
                         &Ks[bufi][p * 2048 + w * 512]);
        }
        #pragma unroll
        for (int p = 0; p < 8; ++p) {
            const int row  = p * 32 + (tid >> 3);            // 0..255
            const int col8 = vslot ^ (row & 7);
            async_copy16(&Vtd[((size_t)b * F_DIM + row) * S_LEN + t + col8 * 8],
                         &Vts[bufi][p * 2048 + w * 512]);
        }
    };

    // prologue: tile 0 into buf 0 (in flight during Q-fragment loads)
    STAGE(0, 0);

    // Q fragments (pre-scaled 1/16 at projection): qf[m][c]
    bf16x8 qf[2][8];
    #pragma unroll
    for (int m = 0; m < 2; ++m) {
        const ushort_t* qrow = &Qd[((size_t)(qw + m * 16 + lo) * B_SZ + b) * F_DIM + hi * 8];
        #pragma unroll
        for (int c = 0; c < 8; ++c)
            qf[m][c] = *reinterpret_cast<const bf16x8*>(&qrow[c * 32]);
    }

    f32x4 O[2][16];
    #pragma unroll
    for (int m = 0; m < 2; ++m)
        #pragma unroll
        for (int fs = 0; fs < 16; ++fs) O[m][fs] = (f32x4){0.f, 0.f, 0.f, 0.f};
    float lacc[2] = {0.f, 0.f};   // per-m partial denom for q-row = lo

    int cur = 0;
    for (int t0 = 0; t0 < S_LEN; t0 += 64, cur ^= 1) {
        // own stage loads for buf[cur] landed; then block-wide sync.
        asm volatile("s_waitcnt vmcnt(0)" ::: "memory");
        __builtin_amdgcn_s_barrier();
        __builtin_amdgcn_sched_barrier(0);

        // issue next tile's loads: land during this tile's compute
        if (t0 + 64 < S_LEN) STAGE(t0 + 64, cur ^ 1);

        const ushort_t* Kc = &Ks[cur][0];
        const ushort_t* Vc = &Vts[cur][0];

        // ---- QK^T, swapped: each kf feeds both m-subtiles ----
        f32x4 sc0[4], sc1[4];
        #pragma unroll
        for (int ks = 0; ks < 4; ++ks) {
            sc0[ks] = (f32x4){0.f, 0.f, 0.f, 0.f};
            sc1[ks] = (f32x4){0.f, 0.f, 0.f, 0.f};
        }
        __builtin_amdgcn_s_setprio(1);
        #pragma unroll
        for (int ks = 0; ks < 4; ++ks) {
            const int krow = ks * 16 + lo;
            const ushort_t* kbase = &Kc[krow * 256];
            const int rx = krow & 7;
            #pragma unroll
            for (int c = 0; c < 8; ++c) {
                const bf16x8 kf = *reinterpret_cast<const bf16x8*>(
                    &kbase[((c * 4 + hi) ^ rx) * 8]);
                sc0[ks] = __builtin_amdgcn_mfma_f32_16x16x32_bf16(kf, qf[0][c], sc0[ks], 0, 0, 0);
                sc1[ks] = __builtin_amdgcn_mfma_f32_16x16x32_bf16(kf, qf[1][c], sc1[ks], 0, 0, 0);
            }
        }
        __builtin_amdgcn_s_setprio(0);

        // ---- softmax-lite + P write, per m (proven byte layout) ----
        #pragma unroll
        for (int m = 0; m < 2; ++m) {
            const f32x4* sc = m ? sc1 : sc0;
            char* prow_bytes = reinterpret_cast<char*>(&Ps[w][m][0]) + lo * 128;
            const int pxor = (lo & 7) << 4;
            #pragma unroll
            for (int ks = 0; ks < 4; ++ks) {
                const float e0 = __expf(sc[ks][0]);
                const float e1 = __expf(sc[ks][1]);
                const float e2 = __expf(sc[ks][2]);
                const float e3 = __expf(sc[ks][3]);
                lacc[m] += (e0 + e1) + (e2 + e3);
                uint2 u;
                u.x = (uint_t)f2bf(e0) | ((uint_t)f2bf(e1) << 16);
                u.y = (uint_t)f2bf(e2) | ((uint_t)f2bf(e3) << 16);
                *reinterpret_cast<uint2*>(prow_bytes + ((ks * 32 + hi * 8) ^ pxor)) = u;
            }
        }

        // ---- read P back as A-frags, per m ----
        bf16x8 pf[2][2];
        #pragma unroll
        for (int m = 0; m < 2; ++m) {
            const int rx = lo & 7;
            const short* pb = &Ps[w][m][lo * 64];
            pf[m][0] = *reinterpret_cast<const bf16x8*>(&pb[((0 * 4 + hi) ^ rx) * 8]);
            pf[m][1] = *reinterpret_cast<const bf16x8*>(&pb[((1 * 4 + hi) ^ rx) * 8]);
        }

        // ---- PV: each vf feeds both m-subtiles ----
        __builtin_amdgcn_s_setprio(1);
        #pragma unroll
        for (int fs = 0; fs < 16; ++fs) {
            const int vrow = fs * 16 + lo;
            const ushort_t* vbase = &Vc[vrow * 64];
            const int rx = vrow & 7;
            const bf16x8 vf0 = *reinterpret_cast<const bf16x8*>(&vbase[((0 + hi) ^ rx) * 8]);
            const bf16x8 vf1 = *reinterpret_cast<const bf16x8*>(&vbase[((4 + hi) ^ rx) * 8]);
            O[0][fs] = __builtin_amdgcn_mfma_f32_16x16x32_bf16(pf[0][0], vf0, O[0][fs], 0, 0, 0);
            O[0][fs] = __builtin_amdgcn_mfma_f32_16x16x32_bf16(pf[0][1], vf1, O[0][fs], 0, 0, 0);
            O[1][fs] = __builtin_amdgcn_mfma_f32_16x16x32_bf16(pf[1][0], vf0, O[1][fs], 0, 0, 0);
            O[1][fs] = __builtin_amdgcn_mfma_f32_16x16x32_bf16(pf[1][1], vf1, O[1][fs], 0, 0, 0);
        }
        __builtin_amdgcn_s_setprio(0);
    }

    // ---- softmax denom per m: reduce across hi-groups + broadcast ----
    #pragma unroll
    for (int m = 0; m < 2; ++m) {
        float s = lacc[m];
        s += __shfl_xor(s, 16);
        s += __shfl_xor(s, 32);
        float inv[4];
        #pragma unroll
        for (int r = 0; r < 4; ++r)
            inv[r] = 1.0f / __shfl(s, hi * 4 + r);
        #pragma unroll
        for (int r = 0; r < 4; ++r) {
            const size_t rbase = ((size_t)(qw + m * 16 + hi * 4 + r) * B_SZ + b) * F_DIM + lo;
            #pragma unroll
            for (int fs = 0; fs < 16; ++fs)
                out[rbase + fs * 16] = O[m][fs][r] * inv[r];
        }
    }
}

extern "C" void kernel_launch(void* const* d_in, const int* in_sizes, int n_in,
                              void* d_out, int out_size, void* d_ws, size_t ws_size,
                              hipStream_t stream) {
    const float* x  = (const float*)d_in[0];
    const float* Wq = (const float*)d_in[1];
    const float* bq = (const float*)d_in[2];
    const float* Wk = (const float*)d_in[3];
    const float* bk = (const float*)d_in[4];
    const float* Wv = (const float*)d_in[5];
    const float* bv = (const float*)d_in[6];
    float* out = (float*)d_out;

    const size_t elems = (size_t)NROWS * F_DIM;          // 8.4M per tensor
    ushort_t* Qd  = (ushort_t*)d_ws;
    ushort_t* Kd  = Qd + elems;
    ushort_t* Vtd = Kd + elems;                          // 50.33 MB total (proven)
    ushort_t* Wbf = (ushort_t*)d_out;                    // 384 KB pre-attn scratch

    hipLaunchKernelGGL(wconv_kernel, dim3(96), dim3(256), 0, stream,
                       Wq, Wk, Wv, Wbf);
    hipLaunchKernelGGL(qkv_proj_mfma_kernel, dim3(NROWS / 64), dim3(256), 0, stream,
                       x, Wbf, bq, bk, bv, Qd, Kd, Vtd);
    hipLaunchKernelGGL(attn_mfma_kernel, dim3(256), dim3(256), 0, stream,
                       Qd, Kd, Vtd, out);
}

// Round 14
// 138.327 us; speedup vs baseline: 1.2407x; 1.2407x over previous
//
#include <hip/hip_runtime.h>
#include <hip/hip_bf16.h>

#define S_LEN 2048
#define B_SZ  16
#define F_DIM 256
#define NROWS (S_LEN * B_SZ)   // 32768

typedef unsigned short ushort_t;
typedef unsigned int   uint_t;
typedef __attribute__((ext_vector_type(8))) short bf16x8;
typedef __attribute__((ext_vector_type(4))) float f32x4;

__device__ __forceinline__ ushort_t f2bf(float f) {
    uint_t x = __float_as_uint(f);
    uint_t r = x + 0x7fffu + ((x >> 16) & 1u);
    return (ushort_t)(r >> 16);
}

__device__ __forceinline__ bf16x8 pack8(float4 a, float4 b) {
    union { bf16x8 v; __hip_bfloat162 h[4]; } u;
    u.h[0] = __float22bfloat162_rn(make_float2(a.x, a.y));
    u.h[1] = __float22bfloat162_rn(make_float2(a.z, a.w));
    u.h[2] = __float22bfloat162_rn(make_float2(b.x, b.y));
    u.h[3] = __float22bfloat162_rn(make_float2(b.z, b.w));
    return u.v;
}

// async 16B global -> LDS (HW writes lds_base + lane*16; gaddr is per-lane)
__device__ __forceinline__ void async_copy16(const ushort_t* g, ushort_t* l) {
    __builtin_amdgcn_global_load_lds(
        (const __attribute__((address_space(1))) uint_t*)g,
        (__attribute__((address_space(3))) uint_t*)l,
        16, 0, 0);
}

// ---------------------------------------------------------------------------
// Kernel 0: one-time W -> bf16 (q,k,v).  Scratch = d_out (attn overwrites all
// of out afterwards; same-stream ordering -> deterministic every replay).
// ---------------------------------------------------------------------------
__global__ __launch_bounds__(256) void wconv_kernel(
    const float* __restrict__ Wq, const float* __restrict__ Wk,
    const float* __restrict__ Wv, ushort_t* __restrict__ Wbf)
{
    const int idx = blockIdx.x * 256 + threadIdx.x;
    const int mat = idx >> 13;
    const int off = (idx & 8191) * 8;
    const float* W = (mat == 0) ? Wq : (mat == 1) ? Wk : Wv;
    const float4 f0 = *reinterpret_cast<const float4*>(&W[off + 0]);
    const float4 f1 = *reinterpret_cast<const float4*>(&W[off + 4]);
    *reinterpret_cast<bf16x8*>(&Wbf[mat * 65536 + off]) = pack8(f0, f1);
}

// ---------------------------------------------------------------------------
// Kernel 1: MFMA QKV projection (unchanged, R9-proven).  Q pre-scaled 1/16.
// ---------------------------------------------------------------------------
__global__ __launch_bounds__(256, 2) void qkv_proj_mfma_kernel(
    const float* __restrict__ x,
    const ushort_t* __restrict__ Wbf,
    const float* __restrict__ bq, const float* __restrict__ bk,
    const float* __restrict__ bv,
    ushort_t* __restrict__ Qd, ushort_t* __restrict__ Kd, ushort_t* __restrict__ Vtd)
{
    __shared__ ushort_t Xs[64 * 256];

    const int tid = threadIdx.x;
    const int w   = tid >> 6;
    const int l   = tid & 63;
    const int lo  = l & 15;
    const int hi  = l >> 4;
    const int bid = blockIdx.x;
    const int bm  = (bid & 7) * 64 + (bid >> 3);
    const int r0  = bm * 64;
    const int wcol0 = w * 64;

    {
        const int row0  = tid >> 3;
        const int slot0 = (tid & 7) * 4;
        #pragma unroll
        for (int p = 0; p < 2; ++p) {
            const int row = row0 + p * 32;
            const float* xrow = &x[(size_t)(r0 + row) * F_DIM];
            #pragma unroll
            for (int c = 0; c < 4; ++c) {
                const int slot = slot0 + c;
                const float4 f0 = *reinterpret_cast<const float4*>(&xrow[slot * 8 + 0]);
                const float4 f1 = *reinterpret_cast<const float4*>(&xrow[slot * 8 + 4]);
                *reinterpret_cast<bf16x8*>(&Xs[row * 256 + ((slot ^ (row & 7)) * 8)]) = pack8(f0, f1);
            }
        }
    }
    __syncthreads();

    const float* Bias[3] = {bq, bk, bv};

    for (int mat = 0; mat < 3; ++mat) {
        const ushort_t* Wm  = &Wbf[mat * 65536];
        const float*    bias = Bias[mat];

        f32x4 acc[4][4];
        #pragma unroll
        for (int m = 0; m < 4; ++m)
            #pragma unroll
            for (int ks = 0; ks < 4; ++ks) acc[m][ks] = (f32x4){0.f, 0.f, 0.f, 0.f};

        #pragma unroll
        for (int ks = 0; ks < 4; ++ks) {
            bf16x8 wf[8];
            {
                const ushort_t* wrow = &Wm[(size_t)(wcol0 + ks * 16 + lo) * F_DIM + hi * 8];
                #pragma unroll
                for (int c = 0; c < 8; ++c)
                    wf[c] = *reinterpret_cast<const bf16x8*>(&wrow[c * 32]);
            }
            #pragma unroll
            for (int m = 0; m < 4; ++m) {
                const int arow = m * 16 + lo;
                const ushort_t* abase = &Xs[arow * 256];
                const int rx = arow & 7;
                #pragma unroll
                for (int c = 0; c < 8; ++c) {
                    const bf16x8 af = *reinterpret_cast<const bf16x8*>(
                        &abase[((c * 4 + hi) ^ rx) * 8]);
                    acc[m][ks] = __builtin_amdgcn_mfma_f32_16x16x32_bf16(af, wf[c], acc[m][ks], 0, 0, 0);
                }
            }
        }

        if (mat < 2) {
            ushort_t* Y = (mat == 0) ? Qd : Kd;
            const float osc = (mat == 0) ? 0.0625f : 1.0f;
            #pragma unroll
            for (int ks = 0; ks < 4; ++ks) {
                const int col = wcol0 + ks * 16 + lo;
                const float bv_ = bias[col];
                #pragma unroll
                for (int m = 0; m < 4; ++m) {
                    #pragma unroll
                    for (int r = 0; r < 4; ++r) {
                        const int row = r0 + m * 16 + hi * 4 + r;
                        Y[(size_t)row * F_DIM + col] = f2bf((acc[m][ks][r] + bv_) * osc);
                    }
                }
            }
        } else {
            const int s0 = r0 >> 4;
            #pragma unroll
            for (int ks = 0; ks < 4; ++ks) {
                const int f = wcol0 + ks * 16 + lo;
                const float bv_ = bias[f];
                #pragma unroll
                for (int r = 0; r < 4; ++r) {
                    const int b = hi * 4 + r;
                    ushort4 u;
                    u.x = f2bf(acc[0][ks][r] + bv_);
                    u.y = f2bf(acc[1][ks][r] + bv_);
                    u.z = f2bf(acc[2][ks][r] + bv_);
                    u.w = f2bf(acc[3][ks][r] + bv_);
                    *reinterpret_cast<ushort4*>(&Vtd[((size_t)b * F_DIM + f) * S_LEN + s0]) = u;
                }
            }
        }
    }
}

// ---------------------------------------------------------------------------
// Kernel 2: MFMA flash attention — 8 waves = 4 q-subtiles (32q, m=2) x 2
// KEY-HALVES.  Key-split (legal: softmax-lite partial O/l are pure sums over
// keys) restores 2 waves/SIMD while keeping m=2's 2-MFMA-per-LDS-read.
// Buffer pointers computed via runtime offset lambdas (R13's pointer-array
// initializer hit a clang addrspacecast static-init bug).  Async zero-reg
// staging (R11-proven), single raw s_barrier per tile.  Epilogue combines
// key-half partners (w, w+4) through the freed K/V LDS.
// LDS: 2*32(K) + 2*32(V) + 16(P) = 144 KB; grid 256, 512 thr.
// ---------------------------------------------------------------------------
__global__ __launch_bounds__(512, 2) void attn_mfma_kernel(
    const ushort_t* __restrict__ Qd,
    const ushort_t* __restrict__ Kd,
    const ushort_t* __restrict__ Vtd,
    float* __restrict__ out)
{
    __shared__ __align__(16) char smem[147456];   // 144 KB

    auto KS = [&](int bufi) -> ushort_t* {
        return reinterpret_cast<ushort_t*>(smem + bufi * 32768);
    };
    auto VS = [&](int bufi) -> ushort_t* {
        return reinterpret_cast<ushort_t*>(smem + 65536 + bufi * 32768);
    };

    const int tid = threadIdx.x;
    const int w   = tid >> 6;            // 0..7
    const int l   = tid & 63;
    const int lo  = l & 15;
    const int hi  = l >> 4;
    const int wq  = w & 3;               // q-subtile
    const int kg  = w >> 2;              // key-half

    const int fid = blockIdx.x;
    const int xcd = fid & 7;
    const int i   = fid >> 3;
    const int b   = xcd * 2 + (i >> 4);
    const int q0  = (i & 15) * 128;
    const int qw  = q0 + wq * 32;        // this wave's 32 q-rows

    const int kslot = tid & 31;
    const int vslot = tid & 7;

    // STAGE (R11-proven pattern): 4 K passes + 4 V passes x 512 thr x 16B.
    auto STAGE = [&](int t, int bufi) {
        ushort_t* kb = KS(bufi);
        ushort_t* vb = VS(bufi);
        #pragma unroll
        for (int p = 0; p < 4; ++p) {
            const int row  = p * 16 + (tid >> 5);            // 0..63
            const int col8 = kslot ^ (row & 7);
            async_copy16(&Kd[((size_t)(t + row) * B_SZ + b) * F_DIM + col8 * 8],
                         kb + p * 4096 + w * 512);
        }
        #pragma unroll
        for (int p = 0; p < 4; ++p) {
            const int row  = p * 64 + (tid >> 3);            // 0..255
            const int col8 = vslot ^ (row & 7);
            async_copy16(&Vtd[((size_t)b * F_DIM + row) * S_LEN + t + col8 * 8],
                         vb + p * 4096 + w * 512);
        }
    };

    STAGE(0, 0);   // prologue: tile 0 in flight during Q loads

    // Q fragments (pre-scaled 1/16): qf[m][c] for q-rows qw + m*16 + lo
    bf16x8 qf[2][8];
    #pragma unroll
    for (int m = 0; m < 2; ++m) {
        const ushort_t* qrow = &Qd[((size_t)(qw + m * 16 + lo) * B_SZ + b) * F_DIM + hi * 8];
        #pragma unroll
        for (int c = 0; c < 8; ++c)
            qf[m][c] = *reinterpret_cast<const bf16x8*>(&qrow[c * 32]);
    }

    f32x4 O[2][16];
    #pragma unroll
    for (int m = 0; m < 2; ++m)
        #pragma unroll
        for (int fs = 0; fs < 16; ++fs) O[m][fs] = (f32x4){0.f, 0.f, 0.f, 0.f};
    float lacc[2] = {0.f, 0.f};   // per-m partial denom (this key-half), q = lo

    short* PsW = reinterpret_cast<short*>(smem + 131072) + (w * 2) * 512;

    int cur = 0;
    for (int t0 = 0; t0 < S_LEN; t0 += 64, cur ^= 1) {
        asm volatile("s_waitcnt vmcnt(0)" ::: "memory");
        __builtin_amdgcn_s_barrier();
        __builtin_amdgcn_sched_barrier(0);

        if (t0 + 64 < S_LEN) STAGE(t0 + 64, cur ^ 1);

        const ushort_t* Kc = KS(cur);
        const ushort_t* Vc = VS(cur);

        // ---- QK^T, swapped, this key-half: keys kg*32 + ks*16 + hi*4 + r
        f32x4 sc[2][2];
        #pragma unroll
        for (int m = 0; m < 2; ++m)
            #pragma unroll
            for (int ks = 0; ks < 2; ++ks) sc[m][ks] = (f32x4){0.f, 0.f, 0.f, 0.f};
        __builtin_amdgcn_s_setprio(1);
        #pragma unroll
        for (int ks = 0; ks < 2; ++ks) {
            const int krow = kg * 32 + ks * 16 + lo;
            const ushort_t* kbase = &Kc[krow * 256];
            const int rx = krow & 7;
            #pragma unroll
            for (int c = 0; c < 8; ++c) {
                const bf16x8 kf = *reinterpret_cast<const bf16x8*>(
                    &kbase[((c * 4 + hi) ^ rx) * 8]);
                sc[0][ks] = __builtin_amdgcn_mfma_f32_16x16x32_bf16(kf, qf[0][c], sc[0][ks], 0, 0, 0);
                sc[1][ks] = __builtin_amdgcn_mfma_f32_16x16x32_bf16(kf, qf[1][c], sc[1][ks], 0, 0, 0);
            }
        }
        __builtin_amdgcn_s_setprio(0);

        // ---- softmax-lite + P write (64B rows, 2-bit swizzle (lo&3)<<4):
        //      local key = ks*16 + hi*4 + r, q = lo; one b64 store per (m,ks)
        #pragma unroll
        for (int m = 0; m < 2; ++m) {
            char* prow_bytes = reinterpret_cast<char*>(PsW + m * 512) + lo * 64;
            const int pxor = (lo & 3) << 4;
            #pragma unroll
            for (int ks = 0; ks < 2; ++ks) {
                const float e0 = __expf(sc[m][ks][0]);
                const float e1 = __expf(sc[m][ks][1]);
                const float e2 = __expf(sc[m][ks][2]);
                const float e3 = __expf(sc[m][ks][3]);
                lacc[m] += (e0 + e1) + (e2 + e3);
                uint2 u;
                u.x = (uint_t)f2bf(e0) | ((uint_t)f2bf(e1) << 16);
                u.y = (uint_t)f2bf(e2) | ((uint_t)f2bf(e3) << 16);
                *reinterpret_cast<uint2*>(prow_bytes + ((ks * 32 + hi * 8) ^ pxor)) = u;
            }
        }

        // ---- read P back as A-frags: row q=lo, k = local keys hi*8..+8 ----
        bf16x8 pf[2];
        #pragma unroll
        for (int m = 0; m < 2; ++m) {
            const char* pb = reinterpret_cast<const char*>(PsW + m * 512) + lo * 64;
            pf[m] = *reinterpret_cast<const bf16x8*>(pb + ((hi * 16) ^ ((lo & 3) << 4)));
        }

        // ---- PV, this key-half: vf slot = kg*4 + hi ----
        __builtin_amdgcn_s_setprio(1);
        #pragma unroll
        for (int fs = 0; fs < 16; ++fs) {
            const int vrow = fs * 16 + lo;
            const ushort_t* vbase = &Vc[vrow * 64];
            const int rx = vrow & 7;
            const bf16x8 vf = *reinterpret_cast<const bf16x8*>(
                &vbase[((kg * 4 + hi) ^ rx) * 8]);
            O[0][fs] = __builtin_amdgcn_mfma_f32_16x16x32_bf16(pf[0], vf, O[0][fs], 0, 0, 0);
            O[1][fs] = __builtin_amdgcn_mfma_f32_16x16x32_bf16(pf[1], vf, O[1][fs], 0, 0, 0);
        }
        __builtin_amdgcn_s_setprio(0);
    }

    // ---- reduce lacc across hi-groups (within key-half): l[q=lo] ----
    float lsum[2];
    #pragma unroll
    for (int m = 0; m < 2; ++m) {
        float s = lacc[m];
        s += __shfl_xor(s, 16);
        s += __shfl_xor(s, 32);
        lsum[m] = s;
    }

    // ---- combine key-halves through LDS (reuse K/V dbuf area) ----
    __syncthreads();   // all tile compute done; K/V LDS free
    float* Oex = reinterpret_cast<float*>(smem);            // 4 x 32 KB
    float* lex = reinterpret_cast<float*>(smem + 131072);   // 4 x 32 floats
    if (w >= 4) {
        float* myO = Oex + (size_t)(w - 4) * 8192;
        #pragma unroll
        for (int m = 0; m < 2; ++m) {
            #pragma unroll
            for (int fs = 0; fs < 16; ++fs)
                #pragma unroll
                for (int r = 0; r < 4; ++r)
                    myO[m * 4096 + fs * 256 + (hi * 4 + r) * 16 + lo] = O[m][fs][r];
            if (hi == 0) lex[(w - 4) * 32 + m * 16 + lo] = lsum[m];
        }
    }
    __syncthreads();
    if (w < 4) {
        const float* pO = Oex + (size_t)w * 8192;
        float inv[2][4];
        #pragma unroll
        for (int m = 0; m < 2; ++m) {
            const float ltot = lsum[m] + lex[w * 32 + m * 16 + lo];   // q = lo
            #pragma unroll
            for (int r = 0; r < 4; ++r)
                inv[m][r] = 1.0f / __shfl(ltot, hi * 4 + r);
        }
        #pragma unroll
        for (int m = 0; m < 2; ++m)
            #pragma unroll
            for (int r = 0; r < 4; ++r) {
                const size_t rbase = ((size_t)(qw + m * 16 + hi * 4 + r) * B_SZ + b) * F_DIM + lo;
                #pragma unroll
                for (int fs = 0; fs < 16; ++fs)
                    out[rbase + fs * 16] =
                        (O[m][fs][r] + pO[m * 4096 + fs * 256 + (hi * 4 + r) * 16 + lo]) * inv[m][r];
            }
    }
}

extern "C" void kernel_launch(void* const* d_in, const int* in_sizes, int n_in,
                              void* d_out, int out_size, void* d_ws, size_t ws_size,
                              hipStream_t stream) {
    const float* x  = (const float*)d_in[0];
    const float* Wq = (const float*)d_in[1];
    const float* bq = (const float*)d_in[2];
    const float* Wk = (const float*)d_in[3];
    const float* bk = (const float*)d_in[4];
    const float* Wv = (const float*)d_in[5];
    const float* bv = (const float*)d_in[6];
    float* out = (float*)d_out;

    const size_t elems = (size_t)NROWS * F_DIM;          // 8.4M per tensor
    ushort_t* Qd  = (ushort_t*)d_ws;
    ushort_t* Kd  = Qd + elems;
    ushort_t* Vtd = Kd + elems;                          // 50.33 MB total (proven)
    ushort_t* Wbf = (ushort_t*)d_out;                    // 384 KB pre-attn scratch

    hipLaunchKernelGGL(wconv_kernel, dim3(96), dim3(256), 0, stream,
                       Wq, Wk, Wv, Wbf);
    hipLaunchKernelGGL(qkv_proj_mfma_kernel, dim3(NROWS / 64), dim3(256), 0, stream,
                       x, Wbf, bq, bk, bv, Qd, Kd, Vtd);
    hipLaunchKernelGGL(attn_mfma_kernel, dim3(256), dim3(512), 0, stream,
                       Qd, Kd, Vtd, out);
}

// Round 15
// 133.686 us; speedup vs baseline: 1.2837x; 1.0347x over previous
//
#include <hip/hip_runtime.h>
#include <hip/hip_bf16.h>

#define S_LEN 2048
#define B_SZ  16
#define F_DIM 256
#define NROWS (S_LEN * B_SZ)   // 32768

typedef unsigned short ushort_t;
typedef unsigned int   uint_t;
typedef __attribute__((ext_vector_type(8))) short bf16x8;
typedef __attribute__((ext_vector_type(4))) float f32x4;

__device__ __forceinline__ ushort_t f2bf(float f) {
    uint_t x = __float_as_uint(f);
    uint_t r = x + 0x7fffu + ((x >> 16) & 1u);
    return (ushort_t)(r >> 16);
}

__device__ __forceinline__ bf16x8 pack8(float4 a, float4 b) {
    union { bf16x8 v; __hip_bfloat162 h[4]; } u;
    u.h[0] = __float22bfloat162_rn(make_float2(a.x, a.y));
    u.h[1] = __float22bfloat162_rn(make_float2(a.z, a.w));
    u.h[2] = __float22bfloat162_rn(make_float2(b.x, b.y));
    u.h[3] = __float22bfloat162_rn(make_float2(b.z, b.w));
    return u.v;
}

// async 16B global -> LDS (HW writes lds_base + lane*16; gaddr is per-lane)
__device__ __forceinline__ void async_copy16(const ushort_t* g, ushort_t* l) {
    __builtin_amdgcn_global_load_lds(
        (const __attribute__((address_space(1))) uint_t*)g,
        (__attribute__((address_space(3))) uint_t*)l,
        16, 0, 0);
}

// ---------------------------------------------------------------------------
// Kernel 0: one-time W -> bf16 (q,k,v).  Scratch = d_out (attn overwrites all
// of out afterwards; same-stream ordering -> deterministic every replay).
// ---------------------------------------------------------------------------
__global__ __launch_bounds__(256) void wconv_kernel(
    const float* __restrict__ Wq, const float* __restrict__ Wk,
    const float* __restrict__ Wv, ushort_t* __restrict__ Wbf)
{
    const int idx = blockIdx.x * 256 + threadIdx.x;
    const int mat = idx >> 13;
    const int off = (idx & 8191) * 8;
    const float* W = (mat == 0) ? Wq : (mat == 1) ? Wk : Wv;
    const float4 f0 = *reinterpret_cast<const float4*>(&W[off + 0]);
    const float4 f1 = *reinterpret_cast<const float4*>(&W[off + 4]);
    *reinterpret_cast<bf16x8*>(&Wbf[mat * 65536 + off]) = pack8(f0, f1);
}

// ---------------------------------------------------------------------------
// Kernel 1: MFMA QKV projection (unchanged, R9-proven).  Q pre-scaled 1/16.
// ---------------------------------------------------------------------------
__global__ __launch_bounds__(256, 2) void qkv_proj_mfma_kernel(
    const float* __restrict__ x,
    const ushort_t* __restrict__ Wbf,
    const float* __restrict__ bq, const float* __restrict__ bk,
    const float* __restrict__ bv,
    ushort_t* __restrict__ Qd, ushort_t* __restrict__ Kd, ushort_t* __restrict__ Vtd)
{
    __shared__ ushort_t Xs[64 * 256];

    const int tid = threadIdx.x;
    const int w   = tid >> 6;
    const int l   = tid & 63;
    const int lo  = l & 15;
    const int hi  = l >> 4;
    const int bid = blockIdx.x;
    const int bm  = (bid & 7) * 64 + (bid >> 3);
    const int r0  = bm * 64;
    const int wcol0 = w * 64;

    {
        const int row0  = tid >> 3;
        const int slot0 = (tid & 7) * 4;
        #pragma unroll
        for (int p = 0; p < 2; ++p) {
            const int row = row0 + p * 32;
            const float* xrow = &x[(size_t)(r0 + row) * F_DIM];
            #pragma unroll
            for (int c = 0; c < 4; ++c) {
                const int slot = slot0 + c;
                const float4 f0 = *reinterpret_cast<const float4*>(&xrow[slot * 8 + 0]);
                const float4 f1 = *reinterpret_cast<const float4*>(&xrow[slot * 8 + 4]);
                *reinterpret_cast<bf16x8*>(&Xs[row * 256 + ((slot ^ (row & 7)) * 8)]) = pack8(f0, f1);
            }
        }
    }
    __syncthreads();

    const float* Bias[3] = {bq, bk, bv};

    for (int mat = 0; mat < 3; ++mat) {
        const ushort_t* Wm  = &Wbf[mat * 65536];
        const float*    bias = Bias[mat];

        f32x4 acc[4][4];
        #pragma unroll
        for (int m = 0; m < 4; ++m)
            #pragma unroll
            for (int ks = 0; ks < 4; ++ks) acc[m][ks] = (f32x4){0.f, 0.f, 0.f, 0.f};

        #pragma unroll
        for (int ks = 0; ks < 4; ++ks) {
            bf16x8 wf[8];
            {
                const ushort_t* wrow = &Wm[(size_t)(wcol0 + ks * 16 + lo) * F_DIM + hi * 8];
                #pragma unroll
                for (int c = 0; c < 8; ++c)
                    wf[c] = *reinterpret_cast<const bf16x8*>(&wrow[c * 32]);
            }
            #pragma unroll
            for (int m = 0; m < 4; ++m) {
                const int arow = m * 16 + lo;
                const ushort_t* abase = &Xs[arow * 256];
                const int rx = arow & 7;
                #pragma unroll
                for (int c = 0; c < 8; ++c) {
                    const bf16x8 af = *reinterpret_cast<const bf16x8*>(
                        &abase[((c * 4 + hi) ^ rx) * 8]);
                    acc[m][ks] = __builtin_amdgcn_mfma_f32_16x16x32_bf16(af, wf[c], acc[m][ks], 0, 0, 0);
                }
            }
        }

        if (mat < 2) {
            ushort_t* Y = (mat == 0) ? Qd : Kd;
            const float osc = (mat == 0) ? 0.0625f : 1.0f;
            #pragma unroll
            for (int ks = 0; ks < 4; ++ks) {
                const int col = wcol0 + ks * 16 + lo;
                const float bv_ = bias[col];
                #pragma unroll
                for (int m = 0; m < 4; ++m) {
                    #pragma unroll
                    for (int r = 0; r < 4; ++r) {
                        const int row = r0 + m * 16 + hi * 4 + r;
                        Y[(size_t)row * F_DIM + col] = f2bf((acc[m][ks][r] + bv_) * osc);
                    }
                }
            }
        } else {
            const int s0 = r0 >> 4;
            #pragma unroll
            for (int ks = 0; ks < 4; ++ks) {
                const int f = wcol0 + ks * 16 + lo;
                const float bv_ = bias[f];
                #pragma unroll
                for (int r = 0; r < 4; ++r) {
                    const int b = hi * 4 + r;
                    ushort4 u;
                    u.x = f2bf(acc[0][ks][r] + bv_);
                    u.y = f2bf(acc[1][ks][r] + bv_);
                    u.z = f2bf(acc[2][ks][r] + bv_);
                    u.w = f2bf(acc[3][ks][r] + bv_);
                    *reinterpret_cast<ushort4*>(&Vtd[((size_t)b * F_DIM + f) * S_LEN + s0]) = u;
                }
            }
        }
    }
}

// ---------------------------------------------------------------------------
// Kernel 2: MFMA flash attention — R14 structure (8 waves = 4 q-subtiles x 2
// key-halves, async zero-reg dbuf staging, 1 raw barrier/tile) with the P
// LDS ROUND TRIP REMOVED via key permutation:
//   QK tile ks loads K row kappa(ks,p) = 8*(p>>2) + 2*(p&3) + ks  (bijective;
//   ks=0 -> even rows, ks=1 -> odd rows of the 32-key half).  Then lane
//   (lo,hi) reg r holds S[key = hi*8 + 2r + ks][q=lo] -> the 8 in-lane
//   values are EXACTLY the PV A-frag keys hi*8+j; pf assembles with 4
//   v_cvt_pk packs.  No P LDS, no shuffles, no 8-way-conflict P ops.
//   Bank check: krow&7 = 2u+ks keeps kf reads at 8 lanes/bank-quad (ideal).
// LDS: 2*32(K) + 2*32(V) = 128 KB + 512B epilogue lex = 131584 B.
// ---------------------------------------------------------------------------
__global__ __launch_bounds__(512, 2) void attn_mfma_kernel(
    const ushort_t* __restrict__ Qd,
    const ushort_t* __restrict__ Kd,
    const ushort_t* __restrict__ Vtd,
    float* __restrict__ out)
{
    __shared__ __align__(16) char smem[131584];   // 128 KB K/V dbuf + 512B lex

    auto KS = [&](int bufi) -> ushort_t* {
        return reinterpret_cast<ushort_t*>(smem + bufi * 32768);
    };
    auto VS = [&](int bufi) -> ushort_t* {
        return reinterpret_cast<ushort_t*>(smem + 65536 + bufi * 32768);
    };

    const int tid = threadIdx.x;
    const int w   = tid >> 6;            // 0..7
    const int l   = tid & 63;
    const int lo  = l & 15;
    const int hi  = l >> 4;
    const int wq  = w & 3;               // q-subtile
    const int kg  = w >> 2;              // key-half

    const int fid = blockIdx.x;
    const int xcd = fid & 7;
    const int i   = fid >> 3;
    const int b   = xcd * 2 + (i >> 4);
    const int q0  = (i & 15) * 128;
    const int qw  = q0 + wq * 32;        // this wave's 32 q-rows

    const int kslot = tid & 31;
    const int vslot = tid & 7;

    // STAGE (R11-proven pattern): 4 K passes + 4 V passes x 512 thr x 16B.
    auto STAGE = [&](int t, int bufi) {
        ushort_t* kb = KS(bufi);
        ushort_t* vb = VS(bufi);
        #pragma unroll
        for (int p = 0; p < 4; ++p) {
            const int row  = p * 16 + (tid >> 5);            // 0..63
            const int col8 = kslot ^ (row & 7);
            async_copy16(&Kd[((size_t)(t + row) * B_SZ + b) * F_DIM + col8 * 8],
                         kb + p * 4096 + w * 512);
        }
        #pragma unroll
        for (int p = 0; p < 4; ++p) {
            const int row  = p * 64 + (tid >> 3);            // 0..255
            const int col8 = vslot ^ (row & 7);
            async_copy16(&Vtd[((size_t)b * F_DIM + row) * S_LEN + t + col8 * 8],
                         vb + p * 4096 + w * 512);
        }
    };

    STAGE(0, 0);   // prologue: tile 0 in flight during Q loads

    // Q fragments (pre-scaled 1/16): qf[m][c] for q-rows qw + m*16 + lo
    bf16x8 qf[2][8];
    #pragma unroll
    for (int m = 0; m < 2; ++m) {
        const ushort_t* qrow = &Qd[((size_t)(qw + m * 16 + lo) * B_SZ + b) * F_DIM + hi * 8];
        #pragma unroll
        for (int c = 0; c < 8; ++c)
            qf[m][c] = *reinterpret_cast<const bf16x8*>(&qrow[c * 32]);
    }

    f32x4 O[2][16];
    #pragma unroll
    for (int m = 0; m < 2; ++m)
        #pragma unroll
        for (int fs = 0; fs < 16; ++fs) O[m][fs] = (f32x4){0.f, 0.f, 0.f, 0.f};
    float lacc[2] = {0.f, 0.f};   // per-m partial denom (this key-half), q = lo

    // kappa-permuted K row for QK tile ks (within this key-half):
    // krow_local = 8*(lo>>2) + 2*(lo&3) + ks
    const int krow_base = kg * 32 + ((lo >> 2) << 3) + ((lo & 3) << 1);

    int cur = 0;
    for (int t0 = 0; t0 < S_LEN; t0 += 64, cur ^= 1) {
        asm volatile("s_waitcnt vmcnt(0)" ::: "memory");
        __builtin_amdgcn_s_barrier();
        __builtin_amdgcn_sched_barrier(0);

        if (t0 + 64 < S_LEN) STAGE(t0 + 64, cur ^ 1);

        const ushort_t* Kc = KS(cur);
        const ushort_t* Vc = VS(cur);

        // ---- QK^T, swapped, kappa-permuted rows ----
        f32x4 sc[2][2];
        #pragma unroll
        for (int m = 0; m < 2; ++m)
            #pragma unroll
            for (int ks = 0; ks < 2; ++ks) sc[m][ks] = (f32x4){0.f, 0.f, 0.f, 0.f};
        __builtin_amdgcn_s_setprio(1);
        #pragma unroll
        for (int ks = 0; ks < 2; ++ks) {
            const int krow = krow_base + ks;
            const ushort_t* kbase = &Kc[krow * 256];
            const int rx = krow & 7;
            #pragma unroll
            for (int c = 0; c < 8; ++c) {
                const bf16x8 kf = *reinterpret_cast<const bf16x8*>(
                    &kbase[((c * 4 + hi) ^ rx) * 8]);
                sc[0][ks] = __builtin_amdgcn_mfma_f32_16x16x32_bf16(kf, qf[0][c], sc[0][ks], 0, 0, 0);
                sc[1][ks] = __builtin_amdgcn_mfma_f32_16x16x32_bf16(kf, qf[1][c], sc[1][ks], 0, 0, 0);
            }
        }
        __builtin_amdgcn_s_setprio(0);

        // ---- softmax-lite, P fully in registers ----
        // lane (lo,hi) reg r of tile ks = S[key = kg*32 + hi*8 + 2r + ks][q=lo]
        // PV A-frag needs keys hi*8 + j  ->  j = 2r + ks: pack pairs
        // (ks0_r, ks1_r) -> positions (2r, 2r+1).  4 cvt_pk per m, zero LDS.
        bf16x8 pf[2];
        #pragma unroll
        for (int m = 0; m < 2; ++m) {
            const float e00 = __expf(sc[m][0][0]);
            const float e01 = __expf(sc[m][0][1]);
            const float e02 = __expf(sc[m][0][2]);
            const float e03 = __expf(sc[m][0][3]);
            const float e10 = __expf(sc[m][1][0]);
            const float e11 = __expf(sc[m][1][1]);
            const float e12 = __expf(sc[m][1][2]);
            const float e13 = __expf(sc[m][1][3]);
            lacc[m] += ((e00 + e01) + (e02 + e03)) + ((e10 + e11) + (e12 + e13));
            union { bf16x8 v; __hip_bfloat162 h[4]; } u;
            u.h[0] = __float22bfloat162_rn(make_float2(e00, e10));
            u.h[1] = __float22bfloat162_rn(make_float2(e01, e11));
            u.h[2] = __float22bfloat162_rn(make_float2(e02, e12));
            u.h[3] = __float22bfloat162_rn(make_float2(e03, e13));
            pf[m] = u.v;
        }

        // ---- PV, this key-half: vf slot = kg*4 + hi ----
        __builtin_amdgcn_s_setprio(1);
        #pragma unroll
        for (int fs = 0; fs < 16; ++fs) {
            const int vrow = fs * 16 + lo;
            const ushort_t* vbase = &Vc[vrow * 64];
            const int rx = vrow & 7;
            const bf16x8 vf = *reinterpret_cast<const bf16x8*>(
                &vbase[((kg * 4 + hi) ^ rx) * 8]);
            O[0][fs] = __builtin_amdgcn_mfma_f32_16x16x32_bf16(pf[0], vf, O[0][fs], 0, 0, 0);
            O[1][fs] = __builtin_amdgcn_mfma_f32_16x16x32_bf16(pf[1], vf, O[1][fs], 0, 0, 0);
        }
        __builtin_amdgcn_s_setprio(0);
    }

    // ---- reduce lacc across hi-groups (within key-half): l[q=lo] ----
    float lsum[2];
    #pragma unroll
    for (int m = 0; m < 2; ++m) {
        float s = lacc[m];
        s += __shfl_xor(s, 16);
        s += __shfl_xor(s, 32);
        lsum[m] = s;
    }

    // ---- combine key-halves through LDS (reuse K/V dbuf area) ----
    __syncthreads();   // all tile compute done; K/V LDS free
    float* Oex = reinterpret_cast<float*>(smem);            // 4 x 32 KB
    float* lex = reinterpret_cast<float*>(smem + 131072);   // 4 x 32 floats
    if (w >= 4) {
        float* myO = Oex + (size_t)(w - 4) * 8192;
        #pragma unroll
        for (int m = 0; m < 2; ++m) {
            #pragma unroll
            for (int fs = 0; fs < 16; ++fs)
                #pragma unroll
                for (int r = 0; r < 4; ++r)
                    myO[m * 4096 + fs * 256 + (hi * 4 + r) * 16 + lo] = O[m][fs][r];
            if (hi == 0) lex[(w - 4) * 32 + m * 16 + lo] = lsum[m];
        }
    }
    __syncthreads();
    if (w < 4) {
        const float* pO = Oex + (size_t)w * 8192;
        float inv[2][4];
        #pragma unroll
        for (int m = 0; m < 2; ++m) {
            const float ltot = lsum[m] + lex[w * 32 + m * 16 + lo];   // q = lo
            #pragma unroll
            for (int r = 0; r < 4; ++r)
                inv[m][r] = 1.0f / __shfl(ltot, hi * 4 + r);
        }
        #pragma unroll
        for (int m = 0; m < 2; ++m)
            #pragma unroll
            for (int r = 0; r < 4; ++r) {
                const size_t rbase = ((size_t)(qw + m * 16 + hi * 4 + r) * B_SZ + b) * F_DIM + lo;
                #pragma unroll
                for (int fs = 0; fs < 16; ++fs)
                    out[rbase + fs * 16] =
                        (O[m][fs][r] + pO[m * 4096 + fs * 256 + (hi * 4 + r) * 16 + lo]) * inv[m][r];
            }
    }
}

extern "C" void kernel_launch(void* const* d_in, const int* in_sizes, int n_in,
                              void* d_out, int out_size, void* d_ws, size_t ws_size,
                              hipStream_t stream) {
    const float* x  = (const float*)d_in[0];
    const float* Wq = (const float*)d_in[1];
    const float* bq = (const float*)d_in[2];
    const float* Wk = (const float*)d_in[3];
    const float* bk = (const float*)d_in[4];
    const float* Wv = (const float*)d_in[5];
    const float* bv = (const float*)d_in[6];
    float* out = (float*)d_out;

    const size_t elems = (size_t)NROWS * F_DIM;          // 8.4M per tensor
    ushort_t* Qd  = (ushort_t*)d_ws;
    ushort_t* Kd  = Qd + elems;
    ushort_t* Vtd = Kd + elems;                          // 50.33 MB total (proven)
    ushort_t* Wbf = (ushort_t*)d_out;                    // 384 KB pre-attn scratch

    hipLaunchKernelGGL(wconv_kernel, dim3(96), dim3(256), 0, stream,
                       Wq, Wk, Wv, Wbf);
    hipLaunchKernelGGL(qkv_proj_mfma_kernel, dim3(NROWS / 64), dim3(256), 0, stream,
                       x, Wbf, bq, bk, bv, Qd, Kd, Vtd);
    hipLaunchKernelGGL(attn_mfma_kernel, dim3(256), dim3(512), 0, stream,
                       Qd, Kd, Vtd, out);
}

// Round 17
// 128.761 us; speedup vs baseline: 1.3328x; 1.0382x over previous
//
#include <hip/hip_runtime.h>
#include <hip/hip_bf16.h>

#define S_LEN 2048
#define B_SZ  16
#define F_DIM 256
#define NROWS (S_LEN * B_SZ)   // 32768

typedef unsigned short ushort_t;
typedef unsigned int   uint_t;
typedef __attribute__((ext_vector_type(8))) short bf16x8;
typedef __attribute__((ext_vector_type(4))) float f32x4;

__device__ __forceinline__ ushort_t f2bf(float f) {
    uint_t x = __float_as_uint(f);
    uint_t r = x + 0x7fffu + ((x >> 16) & 1u);
    return (ushort_t)(r >> 16);
}

__device__ __forceinline__ bf16x8 pack8(float4 a, float4 b) {
    union { bf16x8 v; __hip_bfloat162 h[4]; } u;
    u.h[0] = __float22bfloat162_rn(make_float2(a.x, a.y));
    u.h[1] = __float22bfloat162_rn(make_float2(a.z, a.w));
    u.h[2] = __float22bfloat162_rn(make_float2(b.x, b.y));
    u.h[3] = __float22bfloat162_rn(make_float2(b.z, b.w));
    return u.v;
}

// hardware exp2: v_exp_f32 (D = 2^S0).  (exp2f/__exp2f spellings clash with
// glibc math.h macros in this TU -- use the amdgcn builtin directly.)
#define EXP2(x) __builtin_amdgcn_exp2f(x)

// async 16B global -> LDS (HW writes lds_base + lane*16; gaddr is per-lane)
__device__ __forceinline__ void async_copy16(const ushort_t* g, ushort_t* l) {
    __builtin_amdgcn_global_load_lds(
        (const __attribute__((address_space(1))) uint_t*)g,
        (__attribute__((address_space(3))) uint_t*)l,
        16, 0, 0);
}

// ---------------------------------------------------------------------------
// Kernel 0: one-time W -> bf16 (q,k,v).  Scratch = d_out (attn overwrites all
// of out afterwards; same-stream ordering -> deterministic every replay).
// ---------------------------------------------------------------------------
__global__ __launch_bounds__(256) void wconv_kernel(
    const float* __restrict__ Wq, const float* __restrict__ Wk,
    const float* __restrict__ Wv, ushort_t* __restrict__ Wbf)
{
    const int idx = blockIdx.x * 256 + threadIdx.x;
    const int mat = idx >> 13;
    const int off = (idx & 8191) * 8;
    const float* W = (mat == 0) ? Wq : (mat == 1) ? Wk : Wv;
    const float4 f0 = *reinterpret_cast<const float4*>(&W[off + 0]);
    const float4 f1 = *reinterpret_cast<const float4*>(&W[off + 4]);
    *reinterpret_cast<bf16x8*>(&Wbf[mat * 65536 + off]) = pack8(f0, f1);
}

// ---------------------------------------------------------------------------
// Kernel 1: MFMA QKV projection.  Q pre-scaled by (1/16)*log2(e) so the attn
// softmax uses bare v_exp_f32 (exp2).  V stored in octet-blocked transposed
// layout Vt2[b][s>>3][f][s&7]: the block's 4 consecutive s at fixed (b,f)
// are one 8-B-aligned half-octet -> each 64-B line is filled by 2 ADJACENT
// (same-XCD, co-resident) blocks -> write-combining (R15: WRITE_SIZE 148 MB
// vs 50 logical was the proj bottleneck).
// ---------------------------------------------------------------------------
__global__ __launch_bounds__(256, 2) void qkv_proj_mfma_kernel(
    const float* __restrict__ x,
    const ushort_t* __restrict__ Wbf,
    const float* __restrict__ bq, const float* __restrict__ bk,
    const float* __restrict__ bv,
    ushort_t* __restrict__ Qd, ushort_t* __restrict__ Kd, ushort_t* __restrict__ Vtd)
{
    __shared__ ushort_t Xs[64 * 256];

    const int tid = threadIdx.x;
    const int w   = tid >> 6;
    const int l   = tid & 63;
    const int lo  = l & 15;
    const int hi  = l >> 4;
    const int bid = blockIdx.x;
    const int bm  = (bid & 7) * 64 + (bid >> 3);
    const int r0  = bm * 64;
    const int wcol0 = w * 64;

    {
        const int row0  = tid >> 3;
        const int slot0 = (tid & 7) * 4;
        #pragma unroll
        for (int p = 0; p < 2; ++p) {
            const int row = row0 + p * 32;
            const float* xrow = &x[(size_t)(r0 + row) * F_DIM];
            #pragma unroll
            for (int c = 0; c < 4; ++c) {
                const int slot = slot0 + c;
                const float4 f0 = *reinterpret_cast<const float4*>(&xrow[slot * 8 + 0]);
                const float4 f1 = *reinterpret_cast<const float4*>(&xrow[slot * 8 + 4]);
                *reinterpret_cast<bf16x8*>(&Xs[row * 256 + ((slot ^ (row & 7)) * 8)]) = pack8(f0, f1);
            }
        }
    }
    __syncthreads();

    const float* Bias[3] = {bq, bk, bv};

    for (int mat = 0; mat < 3; ++mat) {
        const ushort_t* Wm  = &Wbf[mat * 65536];
        const float*    bias = Bias[mat];

        f32x4 acc[4][4];
        #pragma unroll
        for (int m = 0; m < 4; ++m)
            #pragma unroll
            for (int ks = 0; ks < 4; ++ks) acc[m][ks] = (f32x4){0.f, 0.f, 0.f, 0.f};

        #pragma unroll
        for (int ks = 0; ks < 4; ++ks) {
            bf16x8 wf[8];
            {
                const ushort_t* wrow = &Wm[(size_t)(wcol0 + ks * 16 + lo) * F_DIM + hi * 8];
                #pragma unroll
                for (int c = 0; c < 8; ++c)
                    wf[c] = *reinterpret_cast<const bf16x8*>(&wrow[c * 32]);
            }
            #pragma unroll
            for (int m = 0; m < 4; ++m) {
                const int arow = m * 16 + lo;
                const ushort_t* abase = &Xs[arow * 256];
                const int rx = arow & 7;
                #pragma unroll
                for (int c = 0; c < 8; ++c) {
                    const bf16x8 af = *reinterpret_cast<const bf16x8*>(
                        &abase[((c * 4 + hi) ^ rx) * 8]);
                    acc[m][ks] = __builtin_amdgcn_mfma_f32_16x16x32_bf16(af, wf[c], acc[m][ks], 0, 0, 0);
                }
            }
        }

        if (mat < 2) {
            ushort_t* Y = (mat == 0) ? Qd : Kd;
            // Q pre-scale: (1/sqrt(F)) * log2(e) -> attn exp2 is exact softmax
            const float osc = (mat == 0) ? 0.0625f * 1.44269504088896f : 1.0f;
            #pragma unroll
            for (int ks = 0; ks < 4; ++ks) {
                const int col = wcol0 + ks * 16 + lo;
                const float bv_ = bias[col];
                #pragma unroll
                for (int m = 0; m < 4; ++m) {
                    #pragma unroll
                    for (int r = 0; r < 4; ++r) {
                        const int row = r0 + m * 16 + hi * 4 + r;
                        Y[(size_t)row * F_DIM + col] = f2bf((acc[m][ks][r] + bv_) * osc);
                    }
                }
            }
        } else {
            // V: Vt2[b][s>>3][f][s&7].  s0 = bm*4 (4-aligned in octet);
            // acc[m], m=0..3 are s0..s0+3 -> one 8-B half-octet store.
            const int s0 = r0 >> 4;
            const int sb = s0 >> 3;
            const int so = s0 & 7;           // 0 or 4
            #pragma unroll
            for (int ks = 0; ks < 4; ++ks) {
                const int f = wcol0 + ks * 16 + lo;
                const float bv_ = bias[f];
                #pragma unroll
                for (int r = 0; r < 4; ++r) {
                    const int b = hi * 4 + r;
                    ushort4 u;
                    u.x = f2bf(acc[0][ks][r] + bv_);
                    u.y = f2bf(acc[1][ks][r] + bv_);
                    u.z = f2bf(acc[2][ks][r] + bv_);
                    u.w = f2bf(acc[3][ks][r] + bv_);
                    *reinterpret_cast<ushort4*>(
                        &Vtd[(((size_t)b * 256 + sb) * 256 + f) * 8 + so]) = u;
                }
            }
        }
    }
}

// ---------------------------------------------------------------------------
// Kernel 2: MFMA flash attention (R15 structure, proven: 8 waves = 4 q-subs
// x 2 key-halves, kappa-permuted zero-shuffle P, async zero-reg dbuf staging,
// 1 raw barrier/tile).  Changes vs R15: V global addresses use the Vt2
// octet-blocked layout (same data -> same LDS byte; reads untouched), and
// softmax uses v_exp_f32 directly (Q carries the log2e factor).
// LDS: 2*32(K) + 2*32(V) = 128 KB + 512B epilogue lex = 131584 B.
// ---------------------------------------------------------------------------
__global__ __launch_bounds__(512, 2) void attn_mfma_kernel(
    const ushort_t* __restrict__ Qd,
    const ushort_t* __restrict__ Kd,
    const ushort_t* __restrict__ Vtd,
    float* __restrict__ out)
{
    __shared__ __align__(16) char smem[131584];   // 128 KB K/V dbuf + 512B lex

    auto KS = [&](int bufi) -> ushort_t* {
        return reinterpret_cast<ushort_t*>(smem + bufi * 32768);
    };
    auto VS = [&](int bufi) -> ushort_t* {
        return reinterpret_cast<ushort_t*>(smem + 65536 + bufi * 32768);
    };

    const int tid = threadIdx.x;
    const int w   = tid >> 6;            // 0..7
    const int l   = tid & 63;
    const int lo  = l & 15;
    const int hi  = l >> 4;
    const int wq  = w & 3;               // q-subtile
    const int kg  = w >> 2;              // key-half

    const int fid = blockIdx.x;
    const int xcd = fid & 7;
    const int i   = fid >> 3;
    const int b   = xcd * 2 + (i >> 4);
    const int q0  = (i & 15) * 128;
    const int qw  = q0 + wq * 32;        // this wave's 32 q-rows

    const int kslot = tid & 31;
    const int vslot = tid & 7;

    // STAGE: 4 K passes + 4 V passes x 512 thr x 16B, zero registers.
    // V granule (f=row, octet col8) = Vt2[b][(t>>3)+col8][row][0..7] -- same
    // bytes at the same LDS position as R15's layout.
    auto STAGE = [&](int t, int bufi) {
        ushort_t* kb = KS(bufi);
        ushort_t* vb = VS(bufi);
        #pragma unroll
        for (int p = 0; p < 4; ++p) {
            const int row  = p * 16 + (tid >> 5);            // 0..63
            const int col8 = kslot ^ (row & 7);
            async_copy16(&Kd[((size_t)(t + row) * B_SZ + b) * F_DIM + col8 * 8],
                         kb + p * 4096 + w * 512);
        }
        #pragma unroll
        for (int p = 0; p < 4; ++p) {
            const int row  = p * 64 + (tid >> 3);            // f: 0..255
            const int col8 = vslot ^ (row & 7);
            async_copy16(&Vtd[(((size_t)b * 256 + (t >> 3) + col8) * 256 + row) * 8],
                         vb + p * 4096 + w * 512);
        }
    };

    STAGE(0, 0);   // prologue: tile 0 in flight during Q loads

    // Q fragments (pre-scaled (1/16)*log2e): qf[m][c]
    bf16x8 qf[2][8];
    #pragma unroll
    for (int m = 0; m < 2; ++m) {
        const ushort_t* qrow = &Qd[((size_t)(qw + m * 16 + lo) * B_SZ + b) * F_DIM + hi * 8];
        #pragma unroll
        for (int c = 0; c < 8; ++c)
            qf[m][c] = *reinterpret_cast<const bf16x8*>(&qrow[c * 32]);
    }

    f32x4 O[2][16];
    #pragma unroll
    for (int m = 0; m < 2; ++m)
        #pragma unroll
        for (int fs = 0; fs < 16; ++fs) O[m][fs] = (f32x4){0.f, 0.f, 0.f, 0.f};
    float lacc[2] = {0.f, 0.f};   // per-m partial denom (this key-half), q = lo

    // kappa-permuted K row for QK tile ks (within this key-half):
    // krow_local = 8*(lo>>2) + 2*(lo&3) + ks
    const int krow_base = kg * 32 + ((lo >> 2) << 3) + ((lo & 3) << 1);

    int cur = 0;
    for (int t0 = 0; t0 < S_LEN; t0 += 64, cur ^= 1) {
        asm volatile("s_waitcnt vmcnt(0)" ::: "memory");
        __builtin_amdgcn_s_barrier();
        __builtin_amdgcn_sched_barrier(0);

        if (t0 + 64 < S_LEN) STAGE(t0 + 64, cur ^ 1);

        const ushort_t* Kc = KS(cur);
        const ushort_t* Vc = VS(cur);

        // ---- QK^T, swapped, kappa-permuted rows ----
        f32x4 sc[2][2];
        #pragma unroll
        for (int m = 0; m < 2; ++m)
            #pragma unroll
            for (int ks = 0; ks < 2; ++ks) sc[m][ks] = (f32x4){0.f, 0.f, 0.f, 0.f};
        __builtin_amdgcn_s_setprio(1);
        #pragma unroll
        for (int ks = 0; ks < 2; ++ks) {
            const int krow = krow_base + ks;
            const ushort_t* kbase = &Kc[krow * 256];
            const int rx = krow & 7;
            #pragma unroll
            for (int c = 0; c < 8; ++c) {
                const bf16x8 kf = *reinterpret_cast<const bf16x8*>(
                    &kbase[((c * 4 + hi) ^ rx) * 8]);
                sc[0][ks] = __builtin_amdgcn_mfma_f32_16x16x32_bf16(kf, qf[0][c], sc[0][ks], 0, 0, 0);
                sc[1][ks] = __builtin_amdgcn_mfma_f32_16x16x32_bf16(kf, qf[1][c], sc[1][ks], 0, 0, 0);
            }
        }
        __builtin_amdgcn_s_setprio(0);

        // ---- softmax-lite, P fully in registers (v_exp_f32; Q has log2e) ----
        // lane (lo,hi) reg r of tile ks = S[key = kg*32 + hi*8 + 2r + ks][q=lo]
        bf16x8 pf[2];
        #pragma unroll
        for (int m = 0; m < 2; ++m) {
            const float e00 = EXP2(sc[m][0][0]);
            const float e01 = EXP2(sc[m][0][1]);
            const float e02 = EXP2(sc[m][0][2]);
            const float e03 = EXP2(sc[m][0][3]);
            const float e10 = EXP2(sc[m][1][0]);
            const float e11 = EXP2(sc[m][1][1]);
            const float e12 = EXP2(sc[m][1][2]);
            const float e13 = EXP2(sc[m][1][3]);
            lacc[m] += ((e00 + e01) + (e02 + e03)) + ((e10 + e11) + (e12 + e13));
            union { bf16x8 v; __hip_bfloat162 h[4]; } u;
            u.h[0] = __float22bfloat162_rn(make_float2(e00, e10));
            u.h[1] = __float22bfloat162_rn(make_float2(e01, e11));
            u.h[2] = __float22bfloat162_rn(make_float2(e02, e12));
            u.h[3] = __float22bfloat162_rn(make_float2(e03, e13));
            pf[m] = u.v;
        }

        // ---- PV, this key-half: vf slot = kg*4 + hi ----
        __builtin_amdgcn_s_setprio(1);
        #pragma unroll
        for (int fs = 0; fs < 16; ++fs) {
            const int vrow = fs * 16 + lo;
            const ushort_t* vbase = &Vc[vrow * 64];
            const int rx = vrow & 7;
            const bf16x8 vf = *reinterpret_cast<const bf16x8*>(
                &vbase[((kg * 4 + hi) ^ rx) * 8]);
            O[0][fs] = __builtin_amdgcn_mfma_f32_16x16x32_bf16(pf[0], vf, O[0][fs], 0, 0, 0);
            O[1][fs] = __builtin_amdgcn_mfma_f32_16x16x32_bf16(pf[1], vf, O[1][fs], 0, 0, 0);
        }
        __builtin_amdgcn_s_setprio(0);
    }

    // ---- reduce lacc across hi-groups (within key-half): l[q=lo] ----
    float lsum[2];
    #pragma unroll
    for (int m = 0; m < 2; ++m) {
        float s = lacc[m];
        s += __shfl_xor(s, 16);
        s += __shfl_xor(s, 32);
        lsum[m] = s;
    }

    // ---- combine key-halves through LDS (reuse K/V dbuf area) ----
    __syncthreads();   // all tile compute done; K/V LDS free
    float* Oex = reinterpret_cast<float*>(smem);            // 4 x 32 KB
    float* lex = reinterpret_cast<float*>(smem + 131072);   // 4 x 32 floats
    if (w >= 4) {
        float* myO = Oex + (size_t)(w - 4) * 8192;
        #pragma unroll
        for (int m = 0; m < 2; ++m) {
            #pragma unroll
            for (int fs = 0; fs < 16; ++fs)
                #pragma unroll
                for (int r = 0; r < 4; ++r)
                    myO[m * 4096 + fs * 256 + (hi * 4 + r) * 16 + lo] = O[m][fs][r];
            if (hi == 0) lex[(w - 4) * 32 + m * 16 + lo] = lsum[m];
        }
    }
    __syncthreads();
    if (w < 4) {
        const float* pO = Oex + (size_t)w * 8192;
        float inv[2][4];
        #pragma unroll
        for (int m = 0; m < 2; ++m) {
            const float ltot = lsum[m] + lex[w * 32 + m * 16 + lo];   // q = lo
            #pragma unroll
            for (int r = 0; r < 4; ++r)
                inv[m][r] = 1.0f / __shfl(ltot, hi * 4 + r);
        }
        #pragma unroll
        for (int m = 0; m < 2; ++m)
            #pragma unroll
            for (int r = 0; r < 4; ++r) {
                const size_t rbase = ((size_t)(qw + m * 16 + hi * 4 + r) * B_SZ + b) * F_DIM + lo;
                #pragma unroll
                for (int fs = 0; fs < 16; ++fs)
                    out[rbase + fs * 16] =
                        (O[m][fs][r] + pO[m * 4096 + fs * 256 + (hi * 4 + r) * 16 + lo]) * inv[m][r];
            }
    }
}

extern "C" void kernel_launch(void* const* d_in, const int* in_sizes, int n_in,
                              void* d_out, int out_size, void* d_ws, size_t ws_size,
                              hipStream_t stream) {
    const float* x  = (const float*)d_in[0];
    const float* Wq = (const float*)d_in[1];
    const float* bq = (const float*)d_in[2];
    const float* Wk = (const float*)d_in[3];
    const float* bk = (const float*)d_in[4];
    const float* Wv = (const float*)d_in[5];
    const float* bv = (const float*)d_in[6];
    float* out = (float*)d_out;

    const size_t elems = (size_t)NROWS * F_DIM;          // 8.4M per tensor
    ushort_t* Qd  = (ushort_t*)d_ws;
    ushort_t* Kd  = Qd + elems;
    ushort_t* Vtd = Kd + elems;                          // 48 MiB total (proven)
    ushort_t* Wbf = (ushort_t*)d_out;                    // 384 KB pre-attn scratch

    hipLaunchKernelGGL(wconv_kernel, dim3(96), dim3(256), 0, stream,
                       Wq, Wk, Wv, Wbf);
    hipLaunchKernelGGL(qkv_proj_mfma_kernel, dim3(NROWS / 64), dim3(256), 0, stream,
                       x, Wbf, bq, bk, bv, Qd, Kd, Vtd);
    hipLaunchKernelGGL(attn_mfma_kernel, dim3(256), dim3(512), 0, stream,
                       Qd, Kd, Vtd, out);
}

// Round 18
// 118.250 us; speedup vs baseline: 1.4513x; 1.0889x over previous
//
#include <hip/hip_runtime.h>
#include <hip/hip_bf16.h>

#define S_LEN 2048
#define B_SZ  16
#define F_DIM 256
#define NROWS (S_LEN * B_SZ)   // 32768

typedef unsigned short ushort_t;
typedef unsigned int   uint_t;
typedef __attribute__((ext_vector_type(8))) short bf16x8;
typedef __attribute__((ext_vector_type(4))) float f32x4;

__device__ __forceinline__ ushort_t f2bf(float f) {
    uint_t x = __float_as_uint(f);
    uint_t r = x + 0x7fffu + ((x >> 16) & 1u);
    return (ushort_t)(r >> 16);
}

__device__ __forceinline__ bf16x8 pack8(float4 a, float4 b) {
    union { bf16x8 v; __hip_bfloat162 h[4]; } u;
    u.h[0] = __float22bfloat162_rn(make_float2(a.x, a.y));
    u.h[1] = __float22bfloat162_rn(make_float2(a.z, a.w));
    u.h[2] = __float22bfloat162_rn(make_float2(b.x, b.y));
    u.h[3] = __float22bfloat162_rn(make_float2(b.z, b.w));
    return u.v;
}

// hardware exp2: v_exp_f32 (D = 2^S0).  (exp2f/__exp2f spellings clash with
// glibc math.h macros in this TU -- use the amdgcn builtin directly.)
#define EXP2(x) __builtin_amdgcn_exp2f(x)

// async 16B global -> LDS (HW writes lds_base + lane*16; gaddr is per-lane)
__device__ __forceinline__ void async_copy16(const ushort_t* g, ushort_t* l) {
    __builtin_amdgcn_global_load_lds(
        (const __attribute__((address_space(1))) uint_t*)g,
        (__attribute__((address_space(3))) uint_t*)l,
        16, 0, 0);
}

// ---------------------------------------------------------------------------
// Kernel 0: one-time W -> bf16, PRE-FRAGMENTED for the proj B-frag reads:
//   Wb[mat][c][hi][col][j] = W[col][c*32 + hi*8 + j]   (c:0..7, hi:0..3,
//   col:0..255, j:0..7).  Proj's per-lane fragment load is then 16
//   consecutive 16-B chunks across lo -> fully coalesced (R17: the col-major
//   16B-per-512B W gather was ~4x L2 over-read, ~23 us of proj time).
// Scratch = d_out (attn overwrites all of out afterwards).
// ---------------------------------------------------------------------------
__global__ __launch_bounds__(256) void wconv_kernel(
    const float* __restrict__ Wq, const float* __restrict__ Wk,
    const float* __restrict__ Wv, ushort_t* __restrict__ Wbf)
{
    const int idx = blockIdx.x * 256 + threadIdx.x;   // 0..24575
    const int mat = idx >> 13;
    const int rem = idx & 8191;
    const int c   = rem >> 10;          // 0..7
    const int hi  = (rem >> 8) & 3;     // 0..3
    const int col = rem & 255;          // 0..255
    const float* W = (mat == 0) ? Wq : (mat == 1) ? Wk : Wv;
    const float* src = &W[(size_t)col * F_DIM + c * 32 + hi * 8];
    const float4 f0 = *reinterpret_cast<const float4*>(&src[0]);
    const float4 f1 = *reinterpret_cast<const float4*>(&src[4]);
    *reinterpret_cast<bf16x8*>(&Wbf[(size_t)idx * 8]) = pack8(f0, f1);
}

// ---------------------------------------------------------------------------
// Kernel 1: MFMA QKV projection.  Q pre-scaled by (1/16)*log2(e); V stored
// octet-blocked transposed Vt2[b][s>>3][f][s&7] (R17-proven write-combining).
// W fragments now read from the pre-fragmented Wb layout (coalesced).
// ---------------------------------------------------------------------------
__global__ __launch_bounds__(256, 2) void qkv_proj_mfma_kernel(
    const float* __restrict__ x,
    const ushort_t* __restrict__ Wbf,
    const float* __restrict__ bq, const float* __restrict__ bk,
    const float* __restrict__ bv,
    ushort_t* __restrict__ Qd, ushort_t* __restrict__ Kd, ushort_t* __restrict__ Vtd)
{
    __shared__ ushort_t Xs[64 * 256];

    const int tid = threadIdx.x;
    const int w   = tid >> 6;
    const int l   = tid & 63;
    const int lo  = l & 15;
    const int hi  = l >> 4;
    const int bid = blockIdx.x;
    const int bm  = (bid & 7) * 64 + (bid >> 3);
    const int r0  = bm * 64;
    const int wcol0 = w * 64;

    {
        const int row0  = tid >> 3;
        const int slot0 = (tid & 7) * 4;
        #pragma unroll
        for (int p = 0; p < 2; ++p) {
            const int row = row0 + p * 32;
            const float* xrow = &x[(size_t)(r0 + row) * F_DIM];
            #pragma unroll
            for (int c = 0; c < 4; ++c) {
                const int slot = slot0 + c;
                const float4 f0 = *reinterpret_cast<const float4*>(&xrow[slot * 8 + 0]);
                const float4 f1 = *reinterpret_cast<const float4*>(&xrow[slot * 8 + 4]);
                *reinterpret_cast<bf16x8*>(&Xs[row * 256 + ((slot ^ (row & 7)) * 8)]) = pack8(f0, f1);
            }
        }
    }
    __syncthreads();

    const float* Bias[3] = {bq, bk, bv};

    for (int mat = 0; mat < 3; ++mat) {
        const ushort_t* Wm  = &Wbf[mat * 65536];
        const float*    bias = Bias[mat];

        f32x4 acc[4][4];
        #pragma unroll
        for (int m = 0; m < 4; ++m)
            #pragma unroll
            for (int ks = 0; ks < 4; ++ks) acc[m][ks] = (f32x4){0.f, 0.f, 0.f, 0.f};

        #pragma unroll
        for (int ks = 0; ks < 4; ++ks) {
            // B-frags from pre-fragmented layout: elem j = W[col][c*32+hi*8+j]
            bf16x8 wf[8];
            {
                const int col = wcol0 + ks * 16 + lo;
                #pragma unroll
                for (int c = 0; c < 8; ++c)
                    wf[c] = *reinterpret_cast<const bf16x8*>(
                        &Wm[(size_t)((c * 4 + hi) * 256 + col) * 8]);
            }
            #pragma unroll
            for (int m = 0; m < 4; ++m) {
                const int arow = m * 16 + lo;
                const ushort_t* abase = &Xs[arow * 256];
                const int rx = arow & 7;
                #pragma unroll
                for (int c = 0; c < 8; ++c) {
                    const bf16x8 af = *reinterpret_cast<const bf16x8*>(
                        &abase[((c * 4 + hi) ^ rx) * 8]);
                    acc[m][ks] = __builtin_amdgcn_mfma_f32_16x16x32_bf16(af, wf[c], acc[m][ks], 0, 0, 0);
                }
            }
        }

        if (mat < 2) {
            ushort_t* Y = (mat == 0) ? Qd : Kd;
            // Q pre-scale: (1/sqrt(F)) * log2(e) -> attn exp2 is exact softmax
            const float osc = (mat == 0) ? 0.0625f * 1.44269504088896f : 1.0f;
            #pragma unroll
            for (int ks = 0; ks < 4; ++ks) {
                const int col = wcol0 + ks * 16 + lo;
                const float bv_ = bias[col];
                #pragma unroll
                for (int m = 0; m < 4; ++m) {
                    #pragma unroll
                    for (int r = 0; r < 4; ++r) {
                        const int row = r0 + m * 16 + hi * 4 + r;
                        Y[(size_t)row * F_DIM + col] = f2bf((acc[m][ks][r] + bv_) * osc);
                    }
                }
            }
        } else {
            // V: Vt2[b][s>>3][f][s&7].  s0 = bm*4; acc[m] m=0..3 -> one 8-B store.
            const int s0 = r0 >> 4;
            const int sb = s0 >> 3;
            const int so = s0 & 7;           // 0 or 4
            #pragma unroll
            for (int ks = 0; ks < 4; ++ks) {
                const int f = wcol0 + ks * 16 + lo;
                const float bv_ = bias[f];
                #pragma unroll
                for (int r = 0; r < 4; ++r) {
                    const int b = hi * 4 + r;
                    ushort4 u;
                    u.x = f2bf(acc[0][ks][r] + bv_);
                    u.y = f2bf(acc[1][ks][r] + bv_);
                    u.z = f2bf(acc[2][ks][r] + bv_);
                    u.w = f2bf(acc[3][ks][r] + bv_);
                    *reinterpret_cast<ushort4*>(
                        &Vtd[(((size_t)b * 256 + sb) * 256 + f) * 8 + so]) = u;
                }
            }
        }
    }
}

// ---------------------------------------------------------------------------
// Kernel 2: MFMA flash attention — BYTE-IDENTICAL to the R17 passing version.
// (8 waves = 4 q-subtiles x 2 key-halves, kappa-permuted zero-shuffle P,
// async zero-reg dbuf staging, 1 raw barrier/tile, Vt2 global layout,
// v_exp_f32 softmax with log2e folded into Q.)
// LDS: 2*32(K) + 2*32(V) = 128 KB + 512B epilogue lex = 131584 B.
// ---------------------------------------------------------------------------
__global__ __launch_bounds__(512, 2) void attn_mfma_kernel(
    const ushort_t* __restrict__ Qd,
    const ushort_t* __restrict__ Kd,
    const ushort_t* __restrict__ Vtd,
    float* __restrict__ out)
{
    __shared__ __align__(16) char smem[131584];   // 128 KB K/V dbuf + 512B lex

    auto KS = [&](int bufi) -> ushort_t* {
        return reinterpret_cast<ushort_t*>(smem + bufi * 32768);
    };
    auto VS = [&](int bufi) -> ushort_t* {
        return reinterpret_cast<ushort_t*>(smem + 65536 + bufi * 32768);
    };

    const int tid = threadIdx.x;
    const int w   = tid >> 6;            // 0..7
    const int l   = tid & 63;
    const int lo  = l & 15;
    const int hi  = l >> 4;
    const int wq  = w & 3;               // q-subtile
    const int kg  = w >> 2;              // key-half

    const int fid = blockIdx.x;
    const int xcd = fid & 7;
    const int i   = fid >> 3;
    const int b   = xcd * 2 + (i >> 4);
    const int q0  = (i & 15) * 128;
    const int qw  = q0 + wq * 32;        // this wave's 32 q-rows

    const int kslot = tid & 31;
    const int vslot = tid & 7;

    // STAGE: 4 K passes + 4 V passes x 512 thr x 16B, zero registers.
    auto STAGE = [&](int t, int bufi) {
        ushort_t* kb = KS(bufi);
        ushort_t* vb = VS(bufi);
        #pragma unroll
        for (int p = 0; p < 4; ++p) {
            const int row  = p * 16 + (tid >> 5);            // 0..63
            const int col8 = kslot ^ (row & 7);
            async_copy16(&Kd[((size_t)(t + row) * B_SZ + b) * F_DIM + col8 * 8],
                         kb + p * 4096 + w * 512);
        }
        #pragma unroll
        for (int p = 0; p < 4; ++p) {
            const int row  = p * 64 + (tid >> 3);            // f: 0..255
            const int col8 = vslot ^ (row & 7);
            async_copy16(&Vtd[(((size_t)b * 256 + (t >> 3) + col8) * 256 + row) * 8],
                         vb + p * 4096 + w * 512);
        }
    };

    STAGE(0, 0);   // prologue: tile 0 in flight during Q loads

    // Q fragments (pre-scaled (1/16)*log2e): qf[m][c]
    bf16x8 qf[2][8];
    #pragma unroll
    for (int m = 0; m < 2; ++m) {
        const ushort_t* qrow = &Qd[((size_t)(qw + m * 16 + lo) * B_SZ + b) * F_DIM + hi * 8];
        #pragma unroll
        for (int c = 0; c < 8; ++c)
            qf[m][c] = *reinterpret_cast<const bf16x8*>(&qrow[c * 32]);
    }

    f32x4 O[2][16];
    #pragma unroll
    for (int m = 0; m < 2; ++m)
        #pragma unroll
        for (int fs = 0; fs < 16; ++fs) O[m][fs] = (f32x4){0.f, 0.f, 0.f, 0.f};
    float lacc[2] = {0.f, 0.f};   // per-m partial denom (this key-half), q = lo

    // kappa-permuted K row for QK tile ks (within this key-half):
    // krow_local = 8*(lo>>2) + 2*(lo&3) + ks
    const int krow_base = kg * 32 + ((lo >> 2) << 3) + ((lo & 3) << 1);

    int cur = 0;
    for (int t0 = 0; t0 < S_LEN; t0 += 64, cur ^= 1) {
        asm volatile("s_waitcnt vmcnt(0)" ::: "memory");
        __builtin_amdgcn_s_barrier();
        __builtin_amdgcn_sched_barrier(0);

        if (t0 + 64 < S_LEN) STAGE(t0 + 64, cur ^ 1);

        const ushort_t* Kc = KS(cur);
        const ushort_t* Vc = VS(cur);

        // ---- QK^T, swapped, kappa-permuted rows ----
        f32x4 sc[2][2];
        #pragma unroll
        for (int m = 0; m < 2; ++m)
            #pragma unroll
            for (int ks = 0; ks < 2; ++ks) sc[m][ks] = (f32x4){0.f, 0.f, 0.f, 0.f};
        __builtin_amdgcn_s_setprio(1);
        #pragma unroll
        for (int ks = 0; ks < 2; ++ks) {
            const int krow = krow_base + ks;
            const ushort_t* kbase = &Kc[krow * 256];
            const int rx = krow & 7;
            #pragma unroll
            for (int c = 0; c < 8; ++c) {
                const bf16x8 kf = *reinterpret_cast<const bf16x8*>(
                    &kbase[((c * 4 + hi) ^ rx) * 8]);
                sc[0][ks] = __builtin_amdgcn_mfma_f32_16x16x32_bf16(kf, qf[0][c], sc[0][ks], 0, 0, 0);
                sc[1][ks] = __builtin_amdgcn_mfma_f32_16x16x32_bf16(kf, qf[1][c], sc[1][ks], 0, 0, 0);
            }
        }
        __builtin_amdgcn_s_setprio(0);

        // ---- softmax-lite, P fully in registers (v_exp_f32; Q has log2e) ----
        // lane (lo,hi) reg r of tile ks = S[key = kg*32 + hi*8 + 2r + ks][q=lo]
        bf16x8 pf[2];
        #pragma unroll
        for (int m = 0; m < 2; ++m) {
            const float e00 = EXP2(sc[m][0][0]);
            const float e01 = EXP2(sc[m][0][1]);
            const float e02 = EXP2(sc[m][0][2]);
            const float e03 = EXP2(sc[m][0][3]);
            const float e10 = EXP2(sc[m][1][0]);
            const float e11 = EXP2(sc[m][1][1]);
            const float e12 = EXP2(sc[m][1][2]);
            const float e13 = EXP2(sc[m][1][3]);
            lacc[m] += ((e00 + e01) + (e02 + e03)) + ((e10 + e11) + (e12 + e13));
            union { bf16x8 v; __hip_bfloat162 h[4]; } u;
            u.h[0] = __float22bfloat162_rn(make_float2(e00, e10));
            u.h[1] = __float22bfloat162_rn(make_float2(e01, e11));
            u.h[2] = __float22bfloat162_rn(make_float2(e02, e12));
            u.h[3] = __float22bfloat162_rn(make_float2(e03, e13));
            pf[m] = u.v;
        }

        // ---- PV, this key-half: vf slot = kg*4 + hi ----
        __builtin_amdgcn_s_setprio(1);
        #pragma unroll
        for (int fs = 0; fs < 16; ++fs) {
            const int vrow = fs * 16 + lo;
            const ushort_t* vbase = &Vc[vrow * 64];
            const int rx = vrow & 7;
            const bf16x8 vf = *reinterpret_cast<const bf16x8*>(
                &vbase[((kg * 4 + hi) ^ rx) * 8]);
            O[0][fs] = __builtin_amdgcn_mfma_f32_16x16x32_bf16(pf[0], vf, O[0][fs], 0, 0, 0);
            O[1][fs] = __builtin_amdgcn_mfma_f32_16x16x32_bf16(pf[1], vf, O[1][fs], 0, 0, 0);
        }
        __builtin_amdgcn_s_setprio(0);
    }

    // ---- reduce lacc across hi-groups (within key-half): l[q=lo] ----
    float lsum[2];
    #pragma unroll
    for (int m = 0; m < 2; ++m) {
        float s = lacc[m];
        s += __shfl_xor(s, 16);
        s += __shfl_xor(s, 32);
        lsum[m] = s;
    }

    // ---- combine key-halves through LDS (reuse K/V dbuf area) ----
    __syncthreads();   // all tile compute done; K/V LDS free
    float* Oex = reinterpret_cast<float*>(smem);            // 4 x 32 KB
    float* lex = reinterpret_cast<float*>(smem + 131072);   // 4 x 32 floats
    if (w >= 4) {
        float* myO = Oex + (size_t)(w - 4) * 8192;
        #pragma unroll
        for (int m = 0; m < 2; ++m) {
            #pragma unroll
            for (int fs = 0; fs < 16; ++fs)
                #pragma unroll
                for (int r = 0; r < 4; ++r)
                    myO[m * 4096 + fs * 256 + (hi * 4 + r) * 16 + lo] = O[m][fs][r];
            if (hi == 0) lex[(w - 4) * 32 + m * 16 + lo] = lsum[m];
        }
    }
    __syncthreads();
    if (w < 4) {
        const float* pO = Oex + (size_t)w * 8192;
        float inv[2][4];
        #pragma unroll
        for (int m = 0; m < 2; ++m) {
            const float ltot = lsum[m] + lex[w * 32 + m * 16 + lo];   // q = lo
            #pragma unroll
            for (int r = 0; r < 4; ++r)
                inv[m][r] = 1.0f / __shfl(ltot, hi * 4 + r);
        }
        #pragma unroll
        for (int m = 0; m < 2; ++m)
            #pragma unroll
            for (int r = 0; r < 4; ++r) {
                const size_t rbase = ((size_t)(qw + m * 16 + hi * 4 + r) * B_SZ + b) * F_DIM + lo;
                #pragma unroll
                for (int fs = 0; fs < 16; ++fs)
                    out[rbase + fs * 16] =
                        (O[m][fs][r] + pO[m * 4096 + fs * 256 + (hi * 4 + r) * 16 + lo]) * inv[m][r];
            }
    }
}

extern "C" void kernel_launch(void* const* d_in, const int* in_sizes, int n_in,
                              void* d_out, int out_size, void* d_ws, size_t ws_size,
                              hipStream_t stream) {
    const float* x  = (const float*)d_in[0];
    const float* Wq = (const float*)d_in[1];
    const float* bq = (const float*)d_in[2];
    const float* Wk = (const float*)d_in[3];
    const float* bk = (const float*)d_in[4];
    const float* Wv = (const float*)d_in[5];
    const float* bv = (const float*)d_in[6];
    float* out = (float*)d_out;

    const size_t elems = (size_t)NROWS * F_DIM;          // 8.4M per tensor
    ushort_t* Qd  = (ushort_t*)d_ws;
    ushort_t* Kd  = Qd + elems;
    ushort_t* Vtd = Kd + elems;                          // 48 MiB total (proven)
    ushort_t* Wbf = (ushort_t*)d_out;                    // 384 KB pre-attn scratch

    hipLaunchKernelGGL(wconv_kernel, dim3(96), dim3(256), 0, stream,
                       Wq, Wk, Wv, Wbf);
    hipLaunchKernelGGL(qkv_proj_mfma_kernel, dim3(NROWS / 64), dim3(256), 0, stream,
                       x, Wbf, bq, bk, bv, Qd, Kd, Vtd);
    hipLaunchKernelGGL(attn_mfma_kernel, dim3(256), dim3(512), 0, stream,
                       Qd, Kd, Vtd, out);
}

// Round 19
// 114.478 us; speedup vs baseline: 1.4991x; 1.0329x over previous
//
#include <hip/hip_runtime.h>
#include <hip/hip_bf16.h>

#define S_LEN 2048
#define B_SZ  16
#define F_DIM 256
#define NROWS (S_LEN * B_SZ)   // 32768

typedef unsigned short ushort_t;
typedef unsigned int   uint_t;
typedef __attribute__((ext_vector_type(8))) short bf16x8;
typedef __attribute__((ext_vector_type(4))) float f32x4;

__device__ __forceinline__ ushort_t f2bf(float f) {
    uint_t x = __float_as_uint(f);
    uint_t r = x + 0x7fffu + ((x >> 16) & 1u);
    return (ushort_t)(r >> 16);
}

__device__ __forceinline__ bf16x8 pack8(float4 a, float4 b) {
    union { bf16x8 v; __hip_bfloat162 h[4]; } u;
    u.h[0] = __float22bfloat162_rn(make_float2(a.x, a.y));
    u.h[1] = __float22bfloat162_rn(make_float2(a.z, a.w));
    u.h[2] = __float22bfloat162_rn(make_float2(b.x, b.y));
    u.h[3] = __float22bfloat162_rn(make_float2(b.z, b.w));
    return u.v;
}

// hardware exp2: v_exp_f32 (D = 2^S0).
#define EXP2(x) __builtin_amdgcn_exp2f(x)

// async 16B global -> LDS (HW writes lds_base + lane*16; gaddr is per-lane)
__device__ __forceinline__ void async_copy16(const ushort_t* g, ushort_t* l) {
    __builtin_amdgcn_global_load_lds(
        (const __attribute__((address_space(1))) uint_t*)g,
        (__attribute__((address_space(3))) uint_t*)l,
        16, 0, 0);
}

// ---------------------------------------------------------------------------
// Kernel 0: one-time W -> bf16, PRE-FRAGMENTED (R18-proven):
//   Wb[mat][c][hi][col][j] = W[col][c*32 + hi*8 + j]
// Scratch = d_out (attn overwrites all of out afterwards).
// ---------------------------------------------------------------------------
__global__ __launch_bounds__(256) void wconv_kernel(
    const float* __restrict__ Wq, const float* __restrict__ Wk,
    const float* __restrict__ Wv, ushort_t* __restrict__ Wbf)
{
    const int idx = blockIdx.x * 256 + threadIdx.x;   // 0..24575
    const int mat = idx >> 13;
    const int rem = idx & 8191;
    const int c   = rem >> 10;          // 0..7
    const int hi  = (rem >> 8) & 3;     // 0..3
    const int col = rem & 255;          // 0..255
    const float* W = (mat == 0) ? Wq : (mat == 1) ? Wk : Wv;
    const float* src = &W[(size_t)col * F_DIM + c * 32 + hi * 8];
    const float4 f0 = *reinterpret_cast<const float4*>(&src[0]);
    const float4 f1 = *reinterpret_cast<const float4*>(&src[4]);
    *reinterpret_cast<bf16x8*>(&Wbf[(size_t)idx * 8]) = pack8(f0, f1);
}

// ---------------------------------------------------------------------------
// Kernel 1: MFMA QKV projection.  Q pre-scaled (1/16)*log2(e); V in
// octet-blocked Vt2[b][s>>3][f][s&7] (R17-proven).  W frags from the
// pre-fragmented Wb layout (R18-proven).  NEW: Q/K epilogue goes through an
// LDS transpose buffer Ys[64][260] (stride 260 -> 2-bank row shift: the
// fragment-scatter WRITE is 2 lanes/bank = free) and stores with 8 x b128
// per thread -- full 512-B rows per wave (R18: 128 scalar 2-B stores/thread
// were the proj residual).
// ---------------------------------------------------------------------------
__global__ __launch_bounds__(256, 2) void qkv_proj_mfma_kernel(
    const float* __restrict__ x,
    const ushort_t* __restrict__ Wbf,
    const float* __restrict__ bq, const float* __restrict__ bk,
    const float* __restrict__ bv,
    ushort_t* __restrict__ Qd, ushort_t* __restrict__ Kd, ushort_t* __restrict__ Vtd)
{
    __shared__ ushort_t Xs[64 * 256];   // 32 KB  (x tile, swizzled)
    __shared__ ushort_t Ys[64 * 260];   // 33.3 KB (epilogue staging)

    const int tid = threadIdx.x;
    const int w   = tid >> 6;
    const int l   = tid & 63;
    const int lo  = l & 15;
    const int hi  = l >> 4;
    const int bid = blockIdx.x;
    const int bm  = (bid & 7) * 64 + (bid >> 3);
    const int r0  = bm * 64;
    const int wcol0 = w * 64;

    {
        const int row0  = tid >> 3;
        const int slot0 = (tid & 7) * 4;
        #pragma unroll
        for (int p = 0; p < 2; ++p) {
            const int row = row0 + p * 32;
            const float* xrow = &x[(size_t)(r0 + row) * F_DIM];
            #pragma unroll
            for (int c = 0; c < 4; ++c) {
                const int slot = slot0 + c;
                const float4 f0 = *reinterpret_cast<const float4*>(&xrow[slot * 8 + 0]);
                const float4 f1 = *reinterpret_cast<const float4*>(&xrow[slot * 8 + 4]);
                *reinterpret_cast<bf16x8*>(&Xs[row * 256 + ((slot ^ (row & 7)) * 8)]) = pack8(f0, f1);
            }
        }
    }
    __syncthreads();

    const float* Bias[3] = {bq, bk, bv};

    for (int mat = 0; mat < 3; ++mat) {
        const ushort_t* Wm  = &Wbf[mat * 65536];
        const float*    bias = Bias[mat];

        f32x4 acc[4][4];
        #pragma unroll
        for (int m = 0; m < 4; ++m)
            #pragma unroll
            for (int ks = 0; ks < 4; ++ks) acc[m][ks] = (f32x4){0.f, 0.f, 0.f, 0.f};

        #pragma unroll
        for (int ks = 0; ks < 4; ++ks) {
            bf16x8 wf[8];
            {
                const int col = wcol0 + ks * 16 + lo;
                #pragma unroll
                for (int c = 0; c < 8; ++c)
                    wf[c] = *reinterpret_cast<const bf16x8*>(
                        &Wm[(size_t)((c * 4 + hi) * 256 + col) * 8]);
            }
            #pragma unroll
            for (int m = 0; m < 4; ++m) {
                const int arow = m * 16 + lo;
                const ushort_t* abase = &Xs[arow * 256];
                const int rx = arow & 7;
                #pragma unroll
                for (int c = 0; c < 8; ++c) {
                    const bf16x8 af = *reinterpret_cast<const bf16x8*>(
                        &abase[((c * 4 + hi) ^ rx) * 8]);
                    acc[m][ks] = __builtin_amdgcn_mfma_f32_16x16x32_bf16(af, wf[c], acc[m][ks], 0, 0, 0);
                }
            }
        }

        if (mat < 2) {
            ushort_t* Y = (mat == 0) ? Qd : Kd;
            // Q pre-scale: (1/sqrt(F)) * log2(e) -> attn exp2 is exact softmax
            const float osc = (mat == 0) ? 0.0625f * 1.44269504088896f : 1.0f;
            // stage fragments into Ys (stride 260)
            #pragma unroll
            for (int ks = 0; ks < 4; ++ks) {
                const int col = wcol0 + ks * 16 + lo;
                const float bv_ = bias[col];
                #pragma unroll
                for (int m = 0; m < 4; ++m) {
                    #pragma unroll
                    for (int r = 0; r < 4; ++r) {
                        const int row = m * 16 + hi * 4 + r;
                        Ys[row * 260 + col] = f2bf((acc[m][ks][r] + bv_) * osc);
                    }
                }
            }
            __syncthreads();
            // coalesced store: 8 x b128 per thread; wave covers full rows
            #pragma unroll
            for (int p = 0; p < 8; ++p) {
                const int idx = p * 2048 + tid * 8;
                const int row = idx >> 8;
                const int col = idx & 255;
                const bf16x8 v = *reinterpret_cast<const bf16x8*>(&Ys[row * 260 + col]);
                *reinterpret_cast<bf16x8*>(&Y[(size_t)(r0 + row) * F_DIM + col]) = v;
            }
            __syncthreads();   // Ys free for next mat
        } else {
            // V: Vt2[b][s>>3][f][s&7] (R17-proven write-combining path)
            const int s0 = r0 >> 4;
            const int sb = s0 >> 3;
            const int so = s0 & 7;           // 0 or 4
            #pragma unroll
            for (int ks = 0; ks < 4; ++ks) {
                const int f = wcol0 + ks * 16 + lo;
                const float bv_ = bias[f];
                #pragma unroll
                for (int r = 0; r < 4; ++r) {
                    const int b = hi * 4 + r;
                    ushort4 u;
                    u.x = f2bf(acc[0][ks][r] + bv_);
                    u.y = f2bf(acc[1][ks][r] + bv_);
                    u.z = f2bf(acc[2][ks][r] + bv_);
                    u.w = f2bf(acc[3][ks][r] + bv_);
                    *reinterpret_cast<ushort4*>(
                        &Vtd[(((size_t)b * 256 + sb) * 256 + f) * 8 + so]) = u;
                }
            }
        }
    }
}

// ---------------------------------------------------------------------------
// Kernel 2: MFMA flash attention — BYTE-IDENTICAL to the R18 passing version.
// (8 waves = 4 q-subtiles x 2 key-halves, kappa-permuted zero-shuffle P,
// async zero-reg dbuf staging, 1 raw barrier/tile, Vt2 global layout,
// v_exp_f32 softmax with log2e folded into Q.)
// ---------------------------------------------------------------------------
__global__ __launch_bounds__(512, 2) void attn_mfma_kernel(
    const ushort_t* __restrict__ Qd,
    const ushort_t* __restrict__ Kd,
    const ushort_t* __restrict__ Vtd,
    float* __restrict__ out)
{
    __shared__ __align__(16) char smem[131584];   // 128 KB K/V dbuf + 512B lex

    auto KS = [&](int bufi) -> ushort_t* {
        return reinterpret_cast<ushort_t*>(smem + bufi * 32768);
    };
    auto VS = [&](int bufi) -> ushort_t* {
        return reinterpret_cast<ushort_t*>(smem + 65536 + bufi * 32768);
    };

    const int tid = threadIdx.x;
    const int w   = tid >> 6;            // 0..7
    const int l   = tid & 63;
    const int lo  = l & 15;
    const int hi  = l >> 4;
    const int wq  = w & 3;               // q-subtile
    const int kg  = w >> 2;              // key-half

    const int fid = blockIdx.x;
    const int xcd = fid & 7;
    const int i   = fid >> 3;
    const int b   = xcd * 2 + (i >> 4);
    const int q0  = (i & 15) * 128;
    const int qw  = q0 + wq * 32;        // this wave's 32 q-rows

    const int kslot = tid & 31;
    const int vslot = tid & 7;

    // STAGE: 4 K passes + 4 V passes x 512 thr x 16B, zero registers.
    auto STAGE = [&](int t, int bufi) {
        ushort_t* kb = KS(bufi);
        ushort_t* vb = VS(bufi);
        #pragma unroll
        for (int p = 0; p < 4; ++p) {
            const int row  = p * 16 + (tid >> 5);            // 0..63
            const int col8 = kslot ^ (row & 7);
            async_copy16(&Kd[((size_t)(t + row) * B_SZ + b) * F_DIM + col8 * 8],
                         kb + p * 4096 + w * 512);
        }
        #pragma unroll
        for (int p = 0; p < 4; ++p) {
            const int row  = p * 64 + (tid >> 3);            // f: 0..255
            const int col8 = vslot ^ (row & 7);
            async_copy16(&Vtd[(((size_t)b * 256 + (t >> 3) + col8) * 256 + row) * 8],
                         vb + p * 4096 + w * 512);
        }
    };

    STAGE(0, 0);   // prologue: tile 0 in flight during Q loads

    // Q fragments (pre-scaled (1/16)*log2e): qf[m][c]
    bf16x8 qf[2][8];
    #pragma unroll
    for (int m = 0; m < 2; ++m) {
        const ushort_t* qrow = &Qd[((size_t)(qw + m * 16 + lo) * B_SZ + b) * F_DIM + hi * 8];
        #pragma unroll
        for (int c = 0; c < 8; ++c)
            qf[m][c] = *reinterpret_cast<const bf16x8*>(&qrow[c * 32]);
    }

    f32x4 O[2][16];
    #pragma unroll
    for (int m = 0; m < 2; ++m)
        #pragma unroll
        for (int fs = 0; fs < 16; ++fs) O[m][fs] = (f32x4){0.f, 0.f, 0.f, 0.f};
    float lacc[2] = {0.f, 0.f};   // per-m partial denom (this key-half), q = lo

    // kappa-permuted K row for QK tile ks (within this key-half):
    // krow_local = 8*(lo>>2) + 2*(lo&3) + ks
    const int krow_base = kg * 32 + ((lo >> 2) << 3) + ((lo & 3) << 1);

    int cur = 0;
    for (int t0 = 0; t0 < S_LEN; t0 += 64, cur ^= 1) {
        asm volatile("s_waitcnt vmcnt(0)" ::: "memory");
        __builtin_amdgcn_s_barrier();
        __builtin_amdgcn_sched_barrier(0);

        if (t0 + 64 < S_LEN) STAGE(t0 + 64, cur ^ 1);

        const ushort_t* Kc = KS(cur);
        const ushort_t* Vc = VS(cur);

        // ---- QK^T, swapped, kappa-permuted rows ----
        f32x4 sc[2][2];
        #pragma unroll
        for (int m = 0; m < 2; ++m)
            #pragma unroll
            for (int ks = 0; ks < 2; ++ks) sc[m][ks] = (f32x4){0.f, 0.f, 0.f, 0.f};
        __builtin_amdgcn_s_setprio(1);
        #pragma unroll
        for (int ks = 0; ks < 2; ++ks) {
            const int krow = krow_base + ks;
            const ushort_t* kbase = &Kc[krow * 256];
            const int rx = krow & 7;
            #pragma unroll
            for (int c = 0; c < 8; ++c) {
                const bf16x8 kf = *reinterpret_cast<const bf16x8*>(
                    &kbase[((c * 4 + hi) ^ rx) * 8]);
                sc[0][ks] = __builtin_amdgcn_mfma_f32_16x16x32_bf16(kf, qf[0][c], sc[0][ks], 0, 0, 0);
                sc[1][ks] = __builtin_amdgcn_mfma_f32_16x16x32_bf16(kf, qf[1][c], sc[1][ks], 0, 0, 0);
            }
        }
        __builtin_amdgcn_s_setprio(0);

        // ---- softmax-lite, P fully in registers (v_exp_f32; Q has log2e) ----
        // lane (lo,hi) reg r of tile ks = S[key = kg*32 + hi*8 + 2r + ks][q=lo]
        bf16x8 pf[2];
        #pragma unroll
        for (int m = 0; m < 2; ++m) {
            const float e00 = EXP2(sc[m][0][0]);
            const float e01 = EXP2(sc[m][0][1]);
            const float e02 = EXP2(sc[m][0][2]);
            const float e03 = EXP2(sc[m][0][3]);
            const float e10 = EXP2(sc[m][1][0]);
            const float e11 = EXP2(sc[m][1][1]);
            const float e12 = EXP2(sc[m][1][2]);
            const float e13 = EXP2(sc[m][1][3]);
            lacc[m] += ((e00 + e01) + (e02 + e03)) + ((e10 + e11) + (e12 + e13));
            union { bf16x8 v; __hip_bfloat162 h[4]; } u;
            u.h[0] = __float22bfloat162_rn(make_float2(e00, e10));
            u.h[1] = __float22bfloat162_rn(make_float2(e01, e11));
            u.h[2] = __float22bfloat162_rn(make_float2(e02, e12));
            u.h[3] = __float22bfloat162_rn(make_float2(e03, e13));
            pf[m] = u.v;
        }

        // ---- PV, this key-half: vf slot = kg*4 + hi ----
        __builtin_amdgcn_s_setprio(1);
        #pragma unroll
        for (int fs = 0; fs < 16; ++fs) {
            const int vrow = fs * 16 + lo;
            const ushort_t* vbase = &Vc[vrow * 64];
            const int rx = vrow & 7;
            const bf16x8 vf = *reinterpret_cast<const bf16x8*>(
                &vbase[((kg * 4 + hi) ^ rx) * 8]);
            O[0][fs] = __builtin_amdgcn_mfma_f32_16x16x32_bf16(pf[0], vf, O[0][fs], 0, 0, 0);
            O[1][fs] = __builtin_amdgcn_mfma_f32_16x16x32_bf16(pf[1], vf, O[1][fs], 0, 0, 0);
        }
        __builtin_amdgcn_s_setprio(0);
    }

    // ---- reduce lacc across hi-groups (within key-half): l[q=lo] ----
    float lsum[2];
    #pragma unroll
    for (int m = 0; m < 2; ++m) {
        float s = lacc[m];
        s += __shfl_xor(s, 16);
        s += __shfl_xor(s, 32);
        lsum[m] = s;
    }

    // ---- combine key-halves through LDS (reuse K/V dbuf area) ----
    __syncthreads();   // all tile compute done; K/V LDS free
    float* Oex = reinterpret_cast<float*>(smem);            // 4 x 32 KB
    float* lex = reinterpret_cast<float*>(smem + 131072);   // 4 x 32 floats
    if (w >= 4) {
        float* myO = Oex + (size_t)(w - 4) * 8192;
        #pragma unroll
        for (int m = 0; m < 2; ++m) {
            #pragma unroll
            for (int fs = 0; fs < 16; ++fs)
                #pragma unroll
                for (int r = 0; r < 4; ++r)
                    myO[m * 4096 + fs * 256 + (hi * 4 + r) * 16 + lo] = O[m][fs][r];
            if (hi == 0) lex[(w - 4) * 32 + m * 16 + lo] = lsum[m];
        }
    }
    __syncthreads();
    if (w < 4) {
        const float* pO = Oex + (size_t)w * 8192;
        float inv[2][4];
        #pragma unroll
        for (int m = 0; m < 2; ++m) {
            const float ltot = lsum[m] + lex[w * 32 + m * 16 + lo];   // q = lo
            #pragma unroll
            for (int r = 0; r < 4; ++r)
                inv[m][r] = 1.0f / __shfl(ltot, hi * 4 + r);
        }
        #pragma unroll
        for (int m = 0; m < 2; ++m)
            #pragma unroll
            for (int r = 0; r < 4; ++r) {
                const size_t rbase = ((size_t)(qw + m * 16 + hi * 4 + r) * B_SZ + b) * F_DIM + lo;
                #pragma unroll
                for (int fs = 0; fs < 16; ++fs)
                    out[rbase + fs * 16] =
                        (O[m][fs][r] + pO[m * 4096 + fs * 256 + (hi * 4 + r) * 16 + lo]) * inv[m][r];
            }
    }
}

extern "C" void kernel_launch(void* const* d_in, const int* in_sizes, int n_in,
                              void* d_out, int out_size, void* d_ws, size_t ws_size,
                              hipStream_t stream) {
    const float* x  = (const float*)d_in[0];
    const float* Wq = (const float*)d_in[1];
    const float* bq = (const float*)d_in[2];
    const float* Wk = (const float*)d_in[3];
    const float* bk = (const float*)d_in[4];
    const float* Wv = (const float*)d_in[5];
    const float* bv = (const float*)d_in[6];
    float* out = (float*)d_out;

    const size_t elems = (size_t)NROWS * F_DIM;          // 8.4M per tensor
    ushort_t* Qd  = (ushort_t*)d_ws;
    ushort_t* Kd  = Qd + elems;
    ushort_t* Vtd = Kd + elems;                          // 48 MiB total (proven)
    ushort_t* Wbf = (ushort_t*)d_out;                    // 384 KB pre-attn scratch

    hipLaunchKernelGGL(wconv_kernel, dim3(96), dim3(256), 0, stream,
                       Wq, Wk, Wv, Wbf);
    hipLaunchKernelGGL(qkv_proj_mfma_kernel, dim3(NROWS / 64), dim3(256), 0, stream,
                       x, Wbf, bq, bk, bv, Qd, Kd, Vtd);
    hipLaunchKernelGGL(attn_mfma_kernel, dim3(256), dim3(512), 0, stream,
                       Qd, Kd, Vtd, out);
}